// Round 14
// baseline (1252.223 us; speedup 1.0000x reference)
//
#include <hip/hip_runtime.h>
#include <hip/hip_bf16.h>
#include <math.h>

namespace {

constexpr int NB   = 16;     // graphs
constexpr int N1   = 4096;   // points per graph
constexpr int K1   = 1024;   // SA1 centers
constexpr int K2   = 256;    // SA2 centers (== first 256 of SA1 centers)
constexpr int MAXN = 32;     // max neighbors
constexpr int RCAP = 448;    // radius candidate capacity per wave

__device__ __forceinline__ float sigmoidf_(float x) {
  return 1.0f / (1.0f + __expf(-x));
}

__device__ __forceinline__ float readlane_f(float v, int l) {
  return __int_as_float(__builtin_amdgcn_readlane(__float_as_int(v), l));
}

// ---------------- Farthest-point sampling (producer) ----------------
// Measured-best structure (4 waves, serial u64-key fold, DPP reduce,
// ping-pong LDS combine). Selections stream to GLOBAL SoA with a release
// counter every 4th selection so consumer blocks can start radius1/conv1
// while FPS is still running. Selection arithmetic unchanged -> bit-exact.

#define FPS_DPP_STEP(CTRL)                                                     \
  {                                                                            \
    const unsigned olo =                                                       \
        (unsigned)__builtin_amdgcn_update_dpp(0, (int)lo, (CTRL), 0xF, 0xF, true); \
    const unsigned ohi =                                                       \
        (unsigned)__builtin_amdgcn_update_dpp(0, (int)hi, (CTRL), 0xF, 0xF, true); \
    const unsigned long long o = ((unsigned long long)ohi << 32) | olo;        \
    const unsigned long long cur = ((unsigned long long)hi << 32) | lo;        \
    if (o > cur) { lo = olo; hi = ohi; }                                       \
  }

template<int NPT>
__device__ __forceinline__ void fps_run(
    const float* __restrict__ sx, const float* __restrict__ sy,
    const float* __restrict__ sz, int k,
    float* __restrict__ dgx, float* __restrict__ dgy, float* __restrict__ dgz,
    int* readyp, unsigned long long (*red)[4]) {
  const int t = threadIdx.x;
  const int lane = t & 63, wave = t >> 6;
  float px[NPT], py[NPT], pz[NPT], mind[NPT];
  unsigned niv[NPT];
  const float c0x = sx[0], c0y = sy[0], c0z = sz[0];
  unsigned long long best = 0;  // identity: dist 0, idx ~0 (never wins)
#pragma unroll
  for (int i = 0; i < NPT; i++) {
    const int p = i * 256 + t;
    niv[i] = ~(unsigned)p;
    px[i] = sx[p]; py[i] = sy[p]; pz[i] = sz[p];
    const float dx = px[i] - c0x, dy = py[i] - c0y, dz = pz[i] - c0z;
    const float d2 = dx * dx + dy * dy + dz * dz;
    mind[i] = d2;
    const unsigned long long cand =
        ((unsigned long long)__float_as_uint(d2) << 32) | niv[i];
    if (cand > best) best = cand;
  }
  if (t == 0) { dgx[0] = c0x; dgy[0] = c0y; dgz[0] = c0z; }
  for (int it = 1; it < k; it++) {
    unsigned lo = (unsigned)best, hi = (unsigned)(best >> 32);
    FPS_DPP_STEP(0x111)  // row_shr:1
    FPS_DPP_STEP(0x112)  // row_shr:2
    FPS_DPP_STEP(0x114)  // row_shr:4
    FPS_DPP_STEP(0x118)  // row_shr:8
    FPS_DPP_STEP(0x142)  // row_bcast:15
    FPS_DPP_STEP(0x143)  // row_bcast:31
    const int par = it & 1;
    if (lane == 63) red[par][wave] = ((unsigned long long)hi << 32) | lo;
    __syncthreads();
    const unsigned long long w0 = red[par][0], w1 = red[par][1];
    const unsigned long long w2 = red[par][2], w3 = red[par][3];
    const unsigned long long m01 = w0 > w1 ? w0 : w1;
    const unsigned long long m23 = w2 > w3 ? w2 : w3;
    const unsigned long long win = m01 > m23 ? m01 : m23;
    const int p = (int)(~(unsigned)win);
    const float nx = sx[p], ny = sy[p], nz = sz[p];
    if (t == 0) {
      dgx[it] = nx; dgy[it] = ny; dgz[it] = nz;
      if ((it & 3) == 3)
        __hip_atomic_store(readyp, it + 1, __ATOMIC_RELEASE,
                           __HIP_MEMORY_SCOPE_AGENT);
    }
    best = 0;
#pragma unroll
    for (int i = 0; i < NPT; i++) {
      const float dx = px[i] - nx, dy = py[i] - ny, dz = pz[i] - nz;
      const float d2 = dx * dx + dy * dy + dz * dz;
      const float m = fminf(mind[i], d2);
      mind[i] = m;
      const unsigned long long cand =
          ((unsigned long long)__float_as_uint(m) << 32) | niv[i];
      if (cand > best) best = cand;
    }
  }
  if (t == 0)
    __hip_atomic_store(readyp, k, __ATOMIC_RELEASE, __HIP_MEMORY_SCOPE_AGENT);
}

#undef FPS_DPP_STEP

// ---------------- radius + 32 nearest -> LDS lists (per wave) ----------
struct RadSmem {
  float candd[4][RCAP];
  int   candi[4][RCAP];
};

__device__ __forceinline__ void radius_lds(
    const float* __restrict__ px, const float* __restrict__ py,
    const float* __restrict__ pz, int N,
    float cx, float cy, float cz, float r2,
    RadSmem& sm, int* nb, int* cntp, int wave, int lane) {
  int total = 0;
  for (int base = 0; base < N; base += 64) {
    const int p = base + lane;
    const float dx = px[p] - cx;
    const float dy = py[p] - cy;
    const float dz = pz[p] - cz;
    const float d2 = dx * dx + dy * dy + dz * dz;
    const bool pred = d2 <= r2;
    const unsigned long long m = __ballot(pred);
    if (pred) {
      const int slot = total + __popcll(m & ((1ull << lane) - 1ull));
      if (slot < RCAP) { sm.candd[wave][slot] = d2; sm.candi[wave][slot] = p; }
    }
    total += __popcll(m);
  }
  if (total > RCAP) total = RCAP;
  if (total <= MAXN) {
    if (lane < total) nb[lane] = sm.candi[wave][lane];
  } else {
    for (int jj = 0; jj < MAXN; jj++) {
      float bvd = INFINITY; int bvi = 0x7fffffff; int bslot = 0;
      for (int s = lane; s < total; s += 64) {
        const float d = sm.candd[wave][s];
        const int i = sm.candi[wave][s];
        if (d < bvd || (d == bvd && i < bvi)) { bvd = d; bvi = i; bslot = s; }
      }
#pragma unroll
      for (int off = 32; off; off >>= 1) {
        const float od = __shfl_xor(bvd, off);
        const int   oi = __shfl_xor(bvi, off);
        const int   os = __shfl_xor(bslot, off);
        if (od < bvd || (od == bvd && oi < bvi)) { bvd = od; bvi = oi; bslot = os; }
      }
      if (lane == 0) { nb[jj] = bvi; sm.candd[wave][bslot] = INFINITY; }
    }
  }
  if (lane == 0) *cntp = (total < MAXN) ? total : MAXN;
}

// ---------------- PointNetConv edge MLP + max agg (one center) ----------
// Rows-in-lanes + readlane broadcast; vectorized weight streaming (round-11
// verified form). nb/V come from LDS (computed in the same block).
template<int CIN_T, int H, int COUT, bool SCALE>
__device__ __forceinline__ void conv_center(
    const float* __restrict__ xin,   // graph base [N][CIN_T]
    const float* __restrict__ ptsx, const float* __restrict__ ptsy,
    const float* __restrict__ ptsz,  // graph base [N]
    float ctrx, float ctry, float ctrz,
    const int* nb, int V,
    const float* __restrict__ w1, const float* __restrict__ b1,
    const float* __restrict__ w2, const float* __restrict__ b2,
    const float* __restrict__ smean, const float* __restrict__ sstd,
    float* __restrict__ outrow, float* part /* LDS [4*COUT] */) {
  constexpr int FIN  = CIN_T + 3;
  constexpr int KREG = (FIN + 63) / 64;
  constexpr int HREG = H / 64;            // h = lane*HREG + q
  constexpr int CREG = COUT / 64;         // c = lane*CREG + q
  constexpr int RPW  = MAXN / 4;
  const int t = threadIdx.x, lane = t & 63, wave = t >> 6;
  float m[CREG];
#pragma unroll
  for (int ck = 0; ck < CREG; ck++) m[ck] = -INFINITY;
  if (V > wave * RPW) {
    float sm = 0.0f, sd = 1.0f;
    if (SCALE && lane < CIN_T) { sm = smean[lane]; sd = sstd[lane]; }
    float fr[RPW][KREG];
#pragma unroll
    for (int r = 0; r < RPW; r++) {
      const int j = wave * RPW + r;
      const int p = (j < V) ? nb[j] : nb[0];
#pragma unroll
      for (int k2 = 0; k2 < KREG; k2++) {
        const int f = k2 * 64 + lane;
        float v = 0.0f;
        if (f < CIN_T) {
          v = xin[(size_t)p * CIN_T + f];
          if constexpr (SCALE) v = (v - sm) / sd;
        } else if (f < FIN) {
          const int d = f - CIN_T;
          const float pv = (d == 0 ? ptsx : (d == 1 ? ptsy : ptsz))[p];
          v = pv - (d == 0 ? ctrx : (d == 1 ? ctry : ctrz));
        }
        fr[r][k2] = v;
      }
    }
    float hh[RPW][HREG];
    {
      float acc[RPW][HREG];
#pragma unroll
      for (int r = 0; r < RPW; r++)
#pragma unroll
        for (int q = 0; q < HREG; q++) acc[r][q] = 0.0f;
#pragma unroll
      for (int k2 = 0; k2 < KREG; k2++) {
        const int lim = (FIN - k2 * 64) < 64 ? (FIN - k2 * 64) : 64;
        for (int fl = 0; fl < lim; fl++) {     // f ascending
          const int f = k2 * 64 + fl;
          float wv[HREG];
          if constexpr (HREG == 1) {
            wv[0] = w1[(size_t)f * H + lane];
          } else {
            const float2 w = *reinterpret_cast<const float2*>(
                &w1[(size_t)f * H + lane * 2]);
            wv[0] = w.x; wv[1] = w.y;
          }
#pragma unroll
          for (int r = 0; r < RPW; r++) {
            const float s = readlane_f(fr[r][k2], fl);
#pragma unroll
            for (int q = 0; q < HREG; q++) acc[r][q] = fmaf(s, wv[q], acc[r][q]);
          }
        }
      }
#pragma unroll
      for (int q = 0; q < HREG; q++) {
        const float bb = b1[lane * HREG + q];
#pragma unroll
        for (int r = 0; r < RPW; r++) hh[r][q] = sigmoidf_(acc[r][q] + bb);
      }
    }
    float acc2[RPW][CREG];
#pragma unroll
    for (int r = 0; r < RPW; r++)
#pragma unroll
      for (int q = 0; q < CREG; q++) acc2[r][q] = 0.0f;
    for (int hl = 0; hl < 64; hl++) {
#pragma unroll
      for (int q1 = 0; q1 < HREG; q1++) {
        const int h = hl * HREG + q1;
        float wv[CREG];
        if constexpr (CREG == 2) {
          const float2 w = *reinterpret_cast<const float2*>(
              &w2[(size_t)h * COUT + lane * 2]);
          wv[0] = w.x; wv[1] = w.y;
        } else {
          const float4 w = *reinterpret_cast<const float4*>(
              &w2[(size_t)h * COUT + lane * 4]);
          wv[0] = w.x; wv[1] = w.y; wv[2] = w.z; wv[3] = w.w;
        }
#pragma unroll
        for (int r = 0; r < RPW; r++) {
          const float s = readlane_f(hh[r][q1], hl);
#pragma unroll
          for (int q = 0; q < CREG; q++) acc2[r][q] = fmaf(s, wv[q], acc2[r][q]);
        }
      }
    }
#pragma unroll
    for (int r = 0; r < RPW; r++) {
      if (wave * RPW + r < V) {
#pragma unroll
        for (int q = 0; q < CREG; q++) m[q] = fmaxf(m[q], acc2[r][q]);
      }
    }
  }
#pragma unroll
  for (int q = 0; q < CREG; q++) part[wave * COUT + lane * CREG + q] = m[q];
  __syncthreads();
  if (t < COUT) {
    const float mm = fmaxf(fmaxf(part[0 * COUT + t], part[1 * COUT + t]),
                           fmaxf(part[2 * COUT + t], part[3 * COUT + t]));
    const float o = mm + b2[t];
    outrow[t] = o > 0.0f ? o : 0.0f;
  }
}

// ---------------- Phase 1 (cooperative): FPS producers + rad1/conv1 --------
// Grid = 256 blocks (1/CU). Blocks 0..NB-1 produce centers; all blocks then
// pull {graph, 4-center} items, spin on the ready counter, and do
// radius1 -> LDS lists -> conv1 (fused; nbr never hits global).
// ctrl layout: [0]=work queue counter, [8+b]=ready count for graph b.
__global__ __launch_bounds__(256) void phase1_kernel(
    const float* __restrict__ pos, const float* __restrict__ x,
    const float* __restrict__ smean, const float* __restrict__ sstd,
    const float* __restrict__ s1w1, const float* __restrict__ s1b1,
    const float* __restrict__ s1w2, const float* __restrict__ s1b2,
    float* __restrict__ pxg, float* __restrict__ pyg, float* __restrict__ pzg,
    float* __restrict__ d1x, float* __restrict__ d1y, float* __restrict__ d1z,
    float* __restrict__ x1, unsigned int* __restrict__ gout,
    int* __restrict__ ctrl) {
  __shared__ __align__(16) char smem[49152];  // fps: sx/sy/sz | worker: RadSmem+
  __shared__ __align__(16) unsigned long long red[2][4];
  __shared__ int s_item;
  const int t = threadIdx.x, lane = t & 63, wave = t >> 6;
  if (blockIdx.x < (unsigned)NB) {
    const int b = blockIdx.x;
    gout[b * 512 + t] = 0u;
    gout[b * 512 + t + 256] = 0u;
    float* sx = (float*)smem; float* sy = sx + N1; float* sz = sy + N1;
    const float* pb = pos + (size_t)b * N1 * 3;
    for (int p = t; p < N1; p += 256) {
      sx[p] = pb[p * 3 + 0]; sy[p] = pb[p * 3 + 1]; sz[p] = pb[p * 3 + 2];
    }
    __syncthreads();
    // SoA point dump (visible to consumers once ready >= 4: release covers it)
    for (int p = t; p < N1; p += 256) {
      pxg[(size_t)b * N1 + p] = sx[p];
      pyg[(size_t)b * N1 + p] = sy[p];
      pzg[(size_t)b * N1 + p] = sz[p];
    }
    fps_run<N1 / 256>(sx, sy, sz, K1,
                      d1x + (size_t)b * K1, d1y + (size_t)b * K1,
                      d1z + (size_t)b * K1, &ctrl[8 + b], red);
    __syncthreads();  // smem reuse as worker scratch
  }
  // ---- persistent worker loop: items = {graph b, center group grp} ----
  RadSmem& rs = *reinterpret_cast<RadSmem*>(smem);
  int* nb_l = reinterpret_cast<int*>(smem + sizeof(RadSmem));  // [4][MAXN]
  int* cnt_l = nb_l + 4 * MAXN;                                // [4]
  float* part = reinterpret_cast<float*>(cnt_l + 4);           // [4*256]
  constexpr int NITEMS = NB * (K1 / 4);
  for (;;) {
    if (t == 0) s_item = atomicAdd(&ctrl[0], 1);
    __syncthreads();
    const int item = s_item;
    __syncthreads();
    if (item >= NITEMS) break;
    const int b = item % NB, grp = item / NB;
    if (t == 0) {
      while (__hip_atomic_load(&ctrl[8 + b], __ATOMIC_ACQUIRE,
                               __HIP_MEMORY_SCOPE_AGENT) < 4 * grp + 4)
        __builtin_amdgcn_s_sleep(16);
    }
    __syncthreads();
    const size_t pB = (size_t)b * N1, cB = (size_t)b * K1;
    const int ci = 4 * grp + wave;
    radius_lds(pxg + pB, pyg + pB, pzg + pB, N1,
               d1x[cB + ci], d1y[cB + ci], d1z[cB + ci], 4.0f,
               rs, nb_l + wave * MAXN, &cnt_l[wave], wave, lane);
    __syncthreads();
    for (int cc = 0; cc < 4; cc++) {
      const int c2 = 4 * grp + cc;
      conv_center<32, 64, 128, true>(
          x + pB * 32, pxg + pB, pyg + pB, pzg + pB,
          d1x[cB + c2], d1y[cB + c2], d1z[cB + c2],
          nb_l + cc * MAXN, cnt_l[cc],
          s1w1, s1b1, s1w2, s1b2, smean, sstd,
          x1 + (cB + c2) * 128, part);
      __syncthreads();
    }
  }
}

// ---------------- Phase 2: radius2 + conv2 fused (normal launch) ----------
__global__ __launch_bounds__(256) void rad2conv2_kernel(
    const float* __restrict__ x1,
    const float* __restrict__ d1x, const float* __restrict__ d1y,
    const float* __restrict__ d1z,
    const float* __restrict__ s2w1, const float* __restrict__ s2b1,
    const float* __restrict__ s2w2, const float* __restrict__ s2b2,
    float* __restrict__ x2) {
  __shared__ __align__(16) RadSmem rs;
  __shared__ int nb_l[4 * MAXN];
  __shared__ int cnt_l[4];
  __shared__ __align__(16) float part[4 * 256];
  const int t = threadIdx.x, lane = t & 63, wave = t >> 6;
  const int b = blockIdx.x % NB, grp = blockIdx.x / NB;  // grp in [0,64)
  const size_t cB = (size_t)b * K1;
  const int ci = 4 * grp + wave;
  radius_lds(d1x + cB, d1y + cB, d1z + cB, K1,
             d1x[cB + ci], d1y[cB + ci], d1z[cB + ci], 16.0f,
             rs, nb_l + wave * MAXN, &cnt_l[wave], wave, lane);
  __syncthreads();
  for (int cc = 0; cc < 4; cc++) {
    const int c2 = 4 * grp + cc;
    conv_center<128, 128, 256, false>(
        x1 + cB * 128, d1x + cB, d1y + cB, d1z + cB,
        d1x[cB + c2], d1y[cB + c2], d1z[cB + c2],
        nb_l + cc * MAXN, cnt_l[cc],
        s2w1, s2b1, s2w2, s2b2, nullptr, nullptr,
        x2 + ((size_t)b * K2 + c2) * 256, part);
    __syncthreads();
  }
}

// ---------------- Global SA: MLP(259->256->512) + relu + max pool ----------
__global__ __launch_bounds__(256) void global_sa_kernel(
    const float* __restrict__ x2,
    const float* __restrict__ d1x, const float* __restrict__ d1y,
    const float* __restrict__ d1z,
    const float* __restrict__ gw1, const float* __restrict__ gb1,
    const float* __restrict__ gw2, const float* __restrict__ gb2,
    unsigned int* __restrict__ gout) {  // [B][512] as float bits (relu >= 0)
  __shared__ float fin[4][259];
  __shared__ float s[4][256];
  const int t = threadIdx.x;
  const int blk = blockIdx.x;
  const int b = blk / 64;
  const int p0 = (blk % 64) * 4;
  for (int item = t; item < 4 * 259; item += 256) {
    const int p = item / 259, f = item - p * 259;
    float v;
    if (f < 256) {
      v = x2[((size_t)b * 256 + p0 + p) * 256 + f];
    } else {
      const int d = f - 256;
      v = (d == 0 ? d1x : (d == 1 ? d1y : d1z))[(size_t)b * K1 + p0 + p];
    }
    fin[p][f] = v;
  }
  __syncthreads();
  float acc[4] = {0.f, 0.f, 0.f, 0.f};
  for (int f = 0; f < 259; f++) {
    const float w = gw1[f * 256 + t];
#pragma unroll
    for (int p = 0; p < 4; p++) acc[p] = fmaf(fin[p][f], w, acc[p]);
  }
  const float bb = gb1[t];
#pragma unroll
  for (int p = 0; p < 4; p++) s[p][t] = sigmoidf_(acc[p] + bb);
  __syncthreads();
  float a0[4] = {0.f, 0.f, 0.f, 0.f}, a1[4] = {0.f, 0.f, 0.f, 0.f};
  for (int h = 0; h < 256; h++) {
    const float w0 = gw2[h * 512 + t];
    const float w1v = gw2[h * 512 + t + 256];
#pragma unroll
    for (int p = 0; p < 4; p++) {
      a0[p] = fmaf(s[p][h], w0, a0[p]);
      a1[p] = fmaf(s[p][h], w1v, a1[p]);
    }
  }
  const float b0 = gb2[t], b1v = gb2[t + 256];
  float m0 = 0.0f, m1 = 0.0f;  // relu floor
#pragma unroll
  for (int p = 0; p < 4; p++) {
    m0 = fmaxf(m0, fmaxf(a0[p] + b0, 0.0f));
    m1 = fmaxf(m1, fmaxf(a1[p] + b1v, 0.0f));
  }
  atomicMax(&gout[b * 512 + t], __float_as_uint(m0));
  atomicMax(&gout[b * 512 + t + 256], __float_as_uint(m1));
}

// ---------------- Final FC head (float32 output) ----------------
__global__ __launch_bounds__(256) void fc_kernel(
    const unsigned int* __restrict__ g,
    const float* __restrict__ fw1, const float* __restrict__ fb1,
    const float* __restrict__ fw2, const float* __restrict__ fb2,
    float* __restrict__ out) {
  __shared__ float gv[512];
  __shared__ float s[256];
  const int b = blockIdx.x, t = threadIdx.x;
  gv[t] = __uint_as_float(g[b * 512 + t]);
  gv[t + 256] = __uint_as_float(g[b * 512 + t + 256]);
  __syncthreads();
  float acc = 0.0f;
  for (int h = 0; h < 512; h++) acc = fmaf(gv[h], fw1[h * 256 + t], acc);
  s[t] = sigmoidf_(acc + fb1[t]);
  __syncthreads();
  if (t < 128) {
    float a2 = 0.0f;
    for (int h = 0; h < 256; h++) a2 = fmaf(s[h], fw2[h * 128 + t], a2);
    const float o = a2 + fb2[t];
    out[b * 128 + t] = o > 0.0f ? o : 0.0f;
  }
}

}  // namespace

extern "C" void kernel_launch(void* const* d_in, const int* in_sizes, int n_in,
                              void* d_out, int out_size, void* d_ws, size_t ws_size,
                              hipStream_t stream) {
  (void)in_sizes; (void)n_in; (void)out_size; (void)ws_size;
  const float* x     = (const float*)d_in[0];
  const float* pos   = (const float*)d_in[1];
  // d_in[2] = batch (int64) — sorted, equal-sized graphs, unused
  const float* smean = (const float*)d_in[3];
  const float* sstd  = (const float*)d_in[4];
  const float* s1w1  = (const float*)d_in[5];
  const float* s1b1  = (const float*)d_in[6];
  const float* s1w2  = (const float*)d_in[7];
  const float* s1b2  = (const float*)d_in[8];
  const float* s2w1  = (const float*)d_in[9];
  const float* s2b1  = (const float*)d_in[10];
  const float* s2w2  = (const float*)d_in[11];
  const float* s2b2  = (const float*)d_in[12];
  const float* gw1   = (const float*)d_in[13];
  const float* gb1   = (const float*)d_in[14];
  const float* gw2   = (const float*)d_in[15];
  const float* gb2   = (const float*)d_in[16];
  const float* fw1   = (const float*)d_in[17];
  const float* fb1   = (const float*)d_in[18];
  const float* fw2   = (const float*)d_in[19];
  const float* fb2   = (const float*)d_in[20];

  char* ws = (char*)d_ws;
  size_t off = 0;
  auto take = [&](size_t bytes) -> char* {
    char* p = ws + off;
    off = (off + bytes + 255) & ~(size_t)255;
    return p;
  };
  float* pxg         = (float*)take((size_t)NB * N1 * 4);
  float* pyg         = (float*)take((size_t)NB * N1 * 4);
  float* pzg         = (float*)take((size_t)NB * N1 * 4);
  float* d1x         = (float*)take((size_t)NB * K1 * 4);
  float* d1y         = (float*)take((size_t)NB * K1 * 4);
  float* d1z         = (float*)take((size_t)NB * K1 * 4);
  float* x1          = (float*)take((size_t)NB * K1 * 128 * 4);
  float* x2          = (float*)take((size_t)NB * K2 * 256 * 4);
  unsigned int* gbuf = (unsigned int*)take((size_t)NB * 512 * 4);
  int* ctrl          = (int*)take(128);   // [0]=q, [8..23]=ready

  hipMemsetAsync(ctrl, 0, 128, stream);

  {
    void* args[] = {
        (void*)&pos, (void*)&x, (void*)&smean, (void*)&sstd,
        (void*)&s1w1, (void*)&s1b1, (void*)&s1w2, (void*)&s1b2,
        (void*)&pxg, (void*)&pyg, (void*)&pzg,
        (void*)&d1x, (void*)&d1y, (void*)&d1z,
        (void*)&x1, (void*)&gbuf, (void*)&ctrl};
    hipLaunchCooperativeKernel((void*)phase1_kernel, dim3(256), dim3(256),
                               args, 0, stream);
  }
  hipLaunchKernelGGL(rad2conv2_kernel, dim3(NB * K2 / 4), dim3(256), 0, stream,
                     x1, d1x, d1y, d1z, s2w1, s2b1, s2w2, s2b2, x2);
  hipLaunchKernelGGL(global_sa_kernel, dim3(NB * 64), dim3(256), 0, stream,
                     x2, d1x, d1y, d1z, gw1, gb1, gw2, gb2, gbuf);
  hipLaunchKernelGGL(fc_kernel, dim3(NB), dim3(256), 0, stream,
                     gbuf, fw1, fb1, fw2, fb2, (float*)d_out);
}

// Round 15
// 1230.908 us; speedup vs baseline: 1.0173x; 1.0173x over previous
//
#include <hip/hip_runtime.h>
#include <hip/hip_bf16.h>
#include <math.h>

namespace {

constexpr int NB   = 16;     // graphs
constexpr int N1   = 4096;   // points per graph
constexpr int K1   = 1024;   // SA1 centers
constexpr int K2   = 256;    // SA2 centers (== first 256 of SA1 centers)
constexpr int MAXN = 32;     // max neighbors
constexpr int RCAP = 448;    // radius candidate capacity per wave

__device__ __forceinline__ float sigmoidf_(float x) {
  return 1.0f / (1.0f + __expf(-x));
}

__device__ __forceinline__ float readlane_f(float v, int l) {
  return __int_as_float(__builtin_amdgcn_readlane(__float_as_int(v), l));
}

// ---------------- Farthest-point sampling (producer) ----------------
// Round-13 measured-best loop (selections -> LDS, zero global traffic per
// iteration) + CHUNKED publish: every 32 selections, wave 0 bulk-copies the
// chunk to global SoA and t0 issues ONE agent-scope release store. The
// release's vmcnt(0) drains exactly wave 0's chunk stores (per-wave counter),
// so no extra barrier. 32 drains/graph instead of 256 (round-14's mistake).

#define FPS_DPP_STEP(CTRL)                                                     \
  {                                                                            \
    const unsigned olo =                                                       \
        (unsigned)__builtin_amdgcn_update_dpp(0, (int)lo, (CTRL), 0xF, 0xF, true); \
    const unsigned ohi =                                                       \
        (unsigned)__builtin_amdgcn_update_dpp(0, (int)hi, (CTRL), 0xF, 0xF, true); \
    const unsigned long long o = ((unsigned long long)ohi << 32) | olo;        \
    const unsigned long long cur = ((unsigned long long)hi << 32) | lo;        \
    if (o > cur) { lo = olo; hi = ohi; }                                       \
  }

template<int NPT>
__device__ __forceinline__ void fps_run(
    const float* __restrict__ sx, const float* __restrict__ sy,
    const float* __restrict__ sz, int k,
    float* __restrict__ selx, float* __restrict__ sely,
    float* __restrict__ selz,                      // LDS, length k
    float* __restrict__ dgx, float* __restrict__ dgy,
    float* __restrict__ dgz,                       // global SoA
    int* readyp, unsigned long long (*red)[4]) {
  const int t = threadIdx.x;
  const int lane = t & 63, wave = t >> 6;
  float px[NPT], py[NPT], pz[NPT], mind[NPT];
  unsigned niv[NPT];
  const float c0x = sx[0], c0y = sy[0], c0z = sz[0];
  unsigned long long best = 0;  // identity: dist 0, idx ~0 (never wins)
#pragma unroll
  for (int i = 0; i < NPT; i++) {
    const int p = i * 256 + t;
    niv[i] = ~(unsigned)p;
    px[i] = sx[p]; py[i] = sy[p]; pz[i] = sz[p];
    const float dx = px[i] - c0x, dy = py[i] - c0y, dz = pz[i] - c0z;
    const float d2 = dx * dx + dy * dy + dz * dz;
    mind[i] = d2;
    const unsigned long long cand =
        ((unsigned long long)__float_as_uint(d2) << 32) | niv[i];
    if (cand > best) best = cand;
  }
  if (t == 0) { selx[0] = c0x; sely[0] = c0y; selz[0] = c0z; }
  for (int it = 1; it < k; it++) {
    unsigned lo = (unsigned)best, hi = (unsigned)(best >> 32);
    FPS_DPP_STEP(0x111)  // row_shr:1
    FPS_DPP_STEP(0x112)  // row_shr:2
    FPS_DPP_STEP(0x114)  // row_shr:4
    FPS_DPP_STEP(0x118)  // row_shr:8
    FPS_DPP_STEP(0x142)  // row_bcast:15
    FPS_DPP_STEP(0x143)  // row_bcast:31
    const int par = it & 1;
    if (lane == 63) red[par][wave] = ((unsigned long long)hi << 32) | lo;
    __syncthreads();
    // ---- chunked publish of selections [it-32, it) (wave 0 only) ----
    if ((it & 31) == 0) {
      const int base = it - 32;
      if (t < 32) {
        dgx[base + t] = selx[base + t];
        dgy[base + t] = sely[base + t];
        dgz[base + t] = selz[base + t];
      }
      if (t == 0)
        __hip_atomic_store(readyp, it, __ATOMIC_RELEASE,
                           __HIP_MEMORY_SCOPE_AGENT);
    }
    const unsigned long long w0 = red[par][0], w1 = red[par][1];
    const unsigned long long w2 = red[par][2], w3 = red[par][3];
    const unsigned long long m01 = w0 > w1 ? w0 : w1;
    const unsigned long long m23 = w2 > w3 ? w2 : w3;
    const unsigned long long win = m01 > m23 ? m01 : m23;
    const int p = (int)(~(unsigned)win);
    const float nx = sx[p], ny = sy[p], nz = sz[p];
    if (t == 0) { selx[it] = nx; sely[it] = ny; selz[it] = nz; }
    best = 0;
#pragma unroll
    for (int i = 0; i < NPT; i++) {
      const float dx = px[i] - nx, dy = py[i] - ny, dz = pz[i] - nz;
      const float d2 = dx * dx + dy * dy + dz * dz;
      const float m = fminf(mind[i], d2);
      mind[i] = m;
      const unsigned long long cand =
          ((unsigned long long)__float_as_uint(m) << 32) | niv[i];
      if (cand > best) best = cand;
    }
  }
  __syncthreads();
  // final chunk [k-32, k) + full-ready flag
  if (t < 32) {
    dgx[k - 32 + t] = selx[k - 32 + t];
    dgy[k - 32 + t] = sely[k - 32 + t];
    dgz[k - 32 + t] = selz[k - 32 + t];
  }
  if (t == 0)
    __hip_atomic_store(readyp, k, __ATOMIC_RELEASE, __HIP_MEMORY_SCOPE_AGENT);
}

#undef FPS_DPP_STEP

// ---------------- radius + 32 nearest -> LDS lists (per wave) ----------
struct RadSmem {
  float candd[4][RCAP];
  int   candi[4][RCAP];
};

__device__ __forceinline__ void radius_lds(
    const float* __restrict__ px, const float* __restrict__ py,
    const float* __restrict__ pz, int N,
    float cx, float cy, float cz, float r2,
    RadSmem& sm, int* nb, int* cntp, int wave, int lane) {
  int total = 0;
  for (int base = 0; base < N; base += 64) {
    const int p = base + lane;
    const float dx = px[p] - cx;
    const float dy = py[p] - cy;
    const float dz = pz[p] - cz;
    const float d2 = dx * dx + dy * dy + dz * dz;
    const bool pred = d2 <= r2;
    const unsigned long long m = __ballot(pred);
    if (pred) {
      const int slot = total + __popcll(m & ((1ull << lane) - 1ull));
      if (slot < RCAP) { sm.candd[wave][slot] = d2; sm.candi[wave][slot] = p; }
    }
    total += __popcll(m);
  }
  if (total > RCAP) total = RCAP;
  if (total <= MAXN) {
    if (lane < total) nb[lane] = sm.candi[wave][lane];
  } else {
    for (int jj = 0; jj < MAXN; jj++) {
      float bvd = INFINITY; int bvi = 0x7fffffff; int bslot = 0;
      for (int s = lane; s < total; s += 64) {
        const float d = sm.candd[wave][s];
        const int i = sm.candi[wave][s];
        if (d < bvd || (d == bvd && i < bvi)) { bvd = d; bvi = i; bslot = s; }
      }
#pragma unroll
      for (int off = 32; off; off >>= 1) {
        const float od = __shfl_xor(bvd, off);
        const int   oi = __shfl_xor(bvi, off);
        const int   os = __shfl_xor(bslot, off);
        if (od < bvd || (od == bvd && oi < bvi)) { bvd = od; bvi = oi; bslot = os; }
      }
      if (lane == 0) { nb[jj] = bvi; sm.candd[wave][bslot] = INFINITY; }
    }
  }
  if (lane == 0) *cntp = (total < MAXN) ? total : MAXN;
}

// ---------------- PointNetConv edge MLP + max agg (one center) ----------
template<int CIN_T, int H, int COUT, bool SCALE>
__device__ __forceinline__ void conv_center(
    const float* __restrict__ xin,   // graph base [N][CIN_T]
    const float* __restrict__ ptsx, const float* __restrict__ ptsy,
    const float* __restrict__ ptsz,  // graph base [N]
    float ctrx, float ctry, float ctrz,
    const int* nb, int V,
    const float* __restrict__ w1, const float* __restrict__ b1,
    const float* __restrict__ w2, const float* __restrict__ b2,
    const float* __restrict__ smean, const float* __restrict__ sstd,
    float* __restrict__ outrow, float* part /* LDS [4*COUT] */) {
  constexpr int FIN  = CIN_T + 3;
  constexpr int KREG = (FIN + 63) / 64;
  constexpr int HREG = H / 64;            // h = lane*HREG + q
  constexpr int CREG = COUT / 64;         // c = lane*CREG + q
  constexpr int RPW  = MAXN / 4;
  const int t = threadIdx.x, lane = t & 63, wave = t >> 6;
  float m[CREG];
#pragma unroll
  for (int ck = 0; ck < CREG; ck++) m[ck] = -INFINITY;
  if (V > wave * RPW) {
    float sm = 0.0f, sd = 1.0f;
    if (SCALE && lane < CIN_T) { sm = smean[lane]; sd = sstd[lane]; }
    float fr[RPW][KREG];
#pragma unroll
    for (int r = 0; r < RPW; r++) {
      const int j = wave * RPW + r;
      const int p = (j < V) ? nb[j] : nb[0];
#pragma unroll
      for (int k2 = 0; k2 < KREG; k2++) {
        const int f = k2 * 64 + lane;
        float v = 0.0f;
        if (f < CIN_T) {
          v = xin[(size_t)p * CIN_T + f];
          if constexpr (SCALE) v = (v - sm) / sd;
        } else if (f < FIN) {
          const int d = f - CIN_T;
          const float pv = (d == 0 ? ptsx : (d == 1 ? ptsy : ptsz))[p];
          v = pv - (d == 0 ? ctrx : (d == 1 ? ctry : ctrz));
        }
        fr[r][k2] = v;
      }
    }
    float hh[RPW][HREG];
    {
      float acc[RPW][HREG];
#pragma unroll
      for (int r = 0; r < RPW; r++)
#pragma unroll
        for (int q = 0; q < HREG; q++) acc[r][q] = 0.0f;
#pragma unroll
      for (int k2 = 0; k2 < KREG; k2++) {
        const int lim = (FIN - k2 * 64) < 64 ? (FIN - k2 * 64) : 64;
        for (int fl = 0; fl < lim; fl++) {     // f ascending
          const int f = k2 * 64 + fl;
          float wv[HREG];
          if constexpr (HREG == 1) {
            wv[0] = w1[(size_t)f * H + lane];
          } else {
            const float2 w = *reinterpret_cast<const float2*>(
                &w1[(size_t)f * H + lane * 2]);
            wv[0] = w.x; wv[1] = w.y;
          }
#pragma unroll
          for (int r = 0; r < RPW; r++) {
            const float s = readlane_f(fr[r][k2], fl);
#pragma unroll
            for (int q = 0; q < HREG; q++) acc[r][q] = fmaf(s, wv[q], acc[r][q]);
          }
        }
      }
#pragma unroll
      for (int q = 0; q < HREG; q++) {
        const float bb = b1[lane * HREG + q];
#pragma unroll
        for (int r = 0; r < RPW; r++) hh[r][q] = sigmoidf_(acc[r][q] + bb);
      }
    }
    float acc2[RPW][CREG];
#pragma unroll
    for (int r = 0; r < RPW; r++)
#pragma unroll
      for (int q = 0; q < CREG; q++) acc2[r][q] = 0.0f;
    for (int hl = 0; hl < 64; hl++) {
#pragma unroll
      for (int q1 = 0; q1 < HREG; q1++) {
        const int h = hl * HREG + q1;
        float wv[CREG];
        if constexpr (CREG == 2) {
          const float2 w = *reinterpret_cast<const float2*>(
              &w2[(size_t)h * COUT + lane * 2]);
          wv[0] = w.x; wv[1] = w.y;
        } else {
          const float4 w = *reinterpret_cast<const float4*>(
              &w2[(size_t)h * COUT + lane * 4]);
          wv[0] = w.x; wv[1] = w.y; wv[2] = w.z; wv[3] = w.w;
        }
#pragma unroll
        for (int r = 0; r < RPW; r++) {
          const float s = readlane_f(hh[r][q1], hl);
#pragma unroll
          for (int q = 0; q < CREG; q++) acc2[r][q] = fmaf(s, wv[q], acc2[r][q]);
        }
      }
    }
#pragma unroll
    for (int r = 0; r < RPW; r++) {
      if (wave * RPW + r < V) {
#pragma unroll
        for (int q = 0; q < CREG; q++) m[q] = fmaxf(m[q], acc2[r][q]);
      }
    }
  }
#pragma unroll
  for (int q = 0; q < CREG; q++) part[wave * COUT + lane * CREG + q] = m[q];
  __syncthreads();
  if (t < COUT) {
    const float mm = fmaxf(fmaxf(part[0 * COUT + t], part[1 * COUT + t]),
                           fmaxf(part[2 * COUT + t], part[3 * COUT + t]));
    const float o = mm + b2[t];
    outrow[t] = o > 0.0f ? o : 0.0f;
  }
}

// ---------------- Phase 1 (cooperative): FPS producers + rad1/conv1 --------
// Grid = 256 blocks (1/CU). Blocks 0..NB-1 produce centers (LDS-resident,
// chunked publish); all blocks pull {graph, 4-center} items, spin on the
// ready counter, then radius1 -> LDS lists -> conv1 fused.
// ctrl layout: [0]=work queue counter, [8+b]=ready count for graph b.
__global__ __launch_bounds__(256) void phase1_kernel(
    const float* __restrict__ pos, const float* __restrict__ x,
    const float* __restrict__ smean, const float* __restrict__ sstd,
    const float* __restrict__ s1w1, const float* __restrict__ s1b1,
    const float* __restrict__ s1w2, const float* __restrict__ s1b2,
    float* __restrict__ pxg, float* __restrict__ pyg, float* __restrict__ pzg,
    float* __restrict__ d1x, float* __restrict__ d1y, float* __restrict__ d1z,
    float* __restrict__ x1, unsigned int* __restrict__ gout,
    int* __restrict__ ctrl) {
  __shared__ __align__(16) char smem[61440];  // fps: pts+sel | worker scratch
  __shared__ __align__(16) unsigned long long red[2][4];
  __shared__ int s_item;
  const int t = threadIdx.x, lane = t & 63, wave = t >> 6;
  if (blockIdx.x < (unsigned)NB) {
    const int b = blockIdx.x;
    gout[b * 512 + t] = 0u;
    gout[b * 512 + t + 256] = 0u;
    float* sx = (float*)smem; float* sy = sx + N1; float* sz = sy + N1;
    float* selx = (float*)(smem + 49152);
    float* sely = selx + K1; float* selz = sely + K1;
    const float* pb = pos + (size_t)b * N1 * 3;
    for (int p = t; p < N1; p += 256) {
      sx[p] = pb[p * 3 + 0]; sy[p] = pb[p * 3 + 1]; sz[p] = pb[p * 3 + 2];
    }
    __syncthreads();
    // SoA point dump; drained to L2 by the next barrier, written back by the
    // first chunk-publish release (wbl2) before any consumer acquires.
    for (int p = t; p < N1; p += 256) {
      pxg[(size_t)b * N1 + p] = sx[p];
      pyg[(size_t)b * N1 + p] = sy[p];
      pzg[(size_t)b * N1 + p] = sz[p];
    }
    __syncthreads();
    fps_run<N1 / 256>(sx, sy, sz, K1, selx, sely, selz,
                      d1x + (size_t)b * K1, d1y + (size_t)b * K1,
                      d1z + (size_t)b * K1, &ctrl[8 + b], red);
    __syncthreads();  // smem reuse as worker scratch
  }
  // ---- persistent worker loop: items = {graph b, center group grp} ----
  RadSmem& rs = *reinterpret_cast<RadSmem*>(smem);
  int* nb_l = reinterpret_cast<int*>(smem + sizeof(RadSmem));  // [4][MAXN]
  int* cnt_l = nb_l + 4 * MAXN;                                // [4]
  float* part = reinterpret_cast<float*>(cnt_l + 4);           // [4*256]
  constexpr int NITEMS = NB * (K1 / 4);
  for (;;) {
    if (t == 0) s_item = atomicAdd(&ctrl[0], 1);
    __syncthreads();
    const int item = s_item;
    __syncthreads();
    if (item >= NITEMS) break;
    const int b = item % NB, grp = item / NB;
    if (t == 0) {
      while (__hip_atomic_load(&ctrl[8 + b], __ATOMIC_ACQUIRE,
                               __HIP_MEMORY_SCOPE_AGENT) < 4 * grp + 4)
        __builtin_amdgcn_s_sleep(64);
    }
    __syncthreads();
    const size_t pB = (size_t)b * N1, cB = (size_t)b * K1;
    const int ci = 4 * grp + wave;
    radius_lds(pxg + pB, pyg + pB, pzg + pB, N1,
               d1x[cB + ci], d1y[cB + ci], d1z[cB + ci], 4.0f,
               rs, nb_l + wave * MAXN, &cnt_l[wave], wave, lane);
    __syncthreads();
    for (int cc = 0; cc < 4; cc++) {
      const int c2 = 4 * grp + cc;
      conv_center<32, 64, 128, true>(
          x + pB * 32, pxg + pB, pyg + pB, pzg + pB,
          d1x[cB + c2], d1y[cB + c2], d1z[cB + c2],
          nb_l + cc * MAXN, cnt_l[cc],
          s1w1, s1b1, s1w2, s1b2, smean, sstd,
          x1 + (cB + c2) * 128, part);
      __syncthreads();
    }
  }
}

// ---------------- Phase 2: radius2 + conv2 fused (normal launch) ----------
__global__ __launch_bounds__(256) void rad2conv2_kernel(
    const float* __restrict__ x1,
    const float* __restrict__ d1x, const float* __restrict__ d1y,
    const float* __restrict__ d1z,
    const float* __restrict__ s2w1, const float* __restrict__ s2b1,
    const float* __restrict__ s2w2, const float* __restrict__ s2b2,
    float* __restrict__ x2) {
  __shared__ __align__(16) RadSmem rs;
  __shared__ int nb_l[4 * MAXN];
  __shared__ int cnt_l[4];
  __shared__ __align__(16) float part[4 * 256];
  const int t = threadIdx.x, lane = t & 63, wave = t >> 6;
  const int b = blockIdx.x % NB, grp = blockIdx.x / NB;  // grp in [0,64)
  const size_t cB = (size_t)b * K1;
  const int ci = 4 * grp + wave;
  radius_lds(d1x + cB, d1y + cB, d1z + cB, K1,
             d1x[cB + ci], d1y[cB + ci], d1z[cB + ci], 16.0f,
             rs, nb_l + wave * MAXN, &cnt_l[wave], wave, lane);
  __syncthreads();
  for (int cc = 0; cc < 4; cc++) {
    const int c2 = 4 * grp + cc;
    conv_center<128, 128, 256, false>(
        x1 + cB * 128, d1x + cB, d1y + cB, d1z + cB,
        d1x[cB + c2], d1y[cB + c2], d1z[cB + c2],
        nb_l + cc * MAXN, cnt_l[cc],
        s2w1, s2b1, s2w2, s2b2, nullptr, nullptr,
        x2 + ((size_t)b * K2 + c2) * 256, part);
    __syncthreads();
  }
}

// ---------------- Global SA: MLP(259->256->512) + relu + max pool ----------
__global__ __launch_bounds__(256) void global_sa_kernel(
    const float* __restrict__ x2,
    const float* __restrict__ d1x, const float* __restrict__ d1y,
    const float* __restrict__ d1z,
    const float* __restrict__ gw1, const float* __restrict__ gb1,
    const float* __restrict__ gw2, const float* __restrict__ gb2,
    unsigned int* __restrict__ gout) {  // [B][512] as float bits (relu >= 0)
  __shared__ float fin[4][259];
  __shared__ float s[4][256];
  const int t = threadIdx.x;
  const int blk = blockIdx.x;
  const int b = blk / 64;
  const int p0 = (blk % 64) * 4;
  for (int item = t; item < 4 * 259; item += 256) {
    const int p = item / 259, f = item - p * 259;
    float v;
    if (f < 256) {
      v = x2[((size_t)b * 256 + p0 + p) * 256 + f];
    } else {
      const int d = f - 256;
      v = (d == 0 ? d1x : (d == 1 ? d1y : d1z))[(size_t)b * K1 + p0 + p];
    }
    fin[p][f] = v;
  }
  __syncthreads();
  float acc[4] = {0.f, 0.f, 0.f, 0.f};
  for (int f = 0; f < 259; f++) {
    const float w = gw1[f * 256 + t];
#pragma unroll
    for (int p = 0; p < 4; p++) acc[p] = fmaf(fin[p][f], w, acc[p]);
  }
  const float bb = gb1[t];
#pragma unroll
  for (int p = 0; p < 4; p++) s[p][t] = sigmoidf_(acc[p] + bb);
  __syncthreads();
  float a0[4] = {0.f, 0.f, 0.f, 0.f}, a1[4] = {0.f, 0.f, 0.f, 0.f};
  for (int h = 0; h < 256; h++) {
    const float w0 = gw2[h * 512 + t];
    const float w1v = gw2[h * 512 + t + 256];
#pragma unroll
    for (int p = 0; p < 4; p++) {
      a0[p] = fmaf(s[p][h], w0, a0[p]);
      a1[p] = fmaf(s[p][h], w1v, a1[p]);
    }
  }
  const float b0 = gb2[t], b1v = gb2[t + 256];
  float m0 = 0.0f, m1 = 0.0f;  // relu floor
#pragma unroll
  for (int p = 0; p < 4; p++) {
    m0 = fmaxf(m0, fmaxf(a0[p] + b0, 0.0f));
    m1 = fmaxf(m1, fmaxf(a1[p] + b1v, 0.0f));
  }
  atomicMax(&gout[b * 512 + t], __float_as_uint(m0));
  atomicMax(&gout[b * 512 + t + 256], __float_as_uint(m1));
}

// ---------------- Final FC head (float32 output) ----------------
__global__ __launch_bounds__(256) void fc_kernel(
    const unsigned int* __restrict__ g,
    const float* __restrict__ fw1, const float* __restrict__ fb1,
    const float* __restrict__ fw2, const float* __restrict__ fb2,
    float* __restrict__ out) {
  __shared__ float gv[512];
  __shared__ float s[256];
  const int b = blockIdx.x, t = threadIdx.x;
  gv[t] = __uint_as_float(g[b * 512 + t]);
  gv[t + 256] = __uint_as_float(g[b * 512 + t + 256]);
  __syncthreads();
  float acc = 0.0f;
  for (int h = 0; h < 512; h++) acc = fmaf(gv[h], fw1[h * 256 + t], acc);
  s[t] = sigmoidf_(acc + fb1[t]);
  __syncthreads();
  if (t < 128) {
    float a2 = 0.0f;
    for (int h = 0; h < 256; h++) a2 = fmaf(s[h], fw2[h * 128 + t], a2);
    const float o = a2 + fb2[t];
    out[b * 128 + t] = o > 0.0f ? o : 0.0f;
  }
}

}  // namespace

extern "C" void kernel_launch(void* const* d_in, const int* in_sizes, int n_in,
                              void* d_out, int out_size, void* d_ws, size_t ws_size,
                              hipStream_t stream) {
  (void)in_sizes; (void)n_in; (void)out_size; (void)ws_size;
  const float* x     = (const float*)d_in[0];
  const float* pos   = (const float*)d_in[1];
  // d_in[2] = batch (int64) — sorted, equal-sized graphs, unused
  const float* smean = (const float*)d_in[3];
  const float* sstd  = (const float*)d_in[4];
  const float* s1w1  = (const float*)d_in[5];
  const float* s1b1  = (const float*)d_in[6];
  const float* s1w2  = (const float*)d_in[7];
  const float* s1b2  = (const float*)d_in[8];
  const float* s2w1  = (const float*)d_in[9];
  const float* s2b1  = (const float*)d_in[10];
  const float* s2w2  = (const float*)d_in[11];
  const float* s2b2  = (const float*)d_in[12];
  const float* gw1   = (const float*)d_in[13];
  const float* gb1   = (const float*)d_in[14];
  const float* gw2   = (const float*)d_in[15];
  const float* gb2   = (const float*)d_in[16];
  const float* fw1   = (const float*)d_in[17];
  const float* fb1   = (const float*)d_in[18];
  const float* fw2   = (const float*)d_in[19];
  const float* fb2   = (const float*)d_in[20];

  char* ws = (char*)d_ws;
  size_t off = 0;
  auto take = [&](size_t bytes) -> char* {
    char* p = ws + off;
    off = (off + bytes + 255) & ~(size_t)255;
    return p;
  };
  float* pxg         = (float*)take((size_t)NB * N1 * 4);
  float* pyg         = (float*)take((size_t)NB * N1 * 4);
  float* pzg         = (float*)take((size_t)NB * N1 * 4);
  float* d1x         = (float*)take((size_t)NB * K1 * 4);
  float* d1y         = (float*)take((size_t)NB * K1 * 4);
  float* d1z         = (float*)take((size_t)NB * K1 * 4);
  float* x1          = (float*)take((size_t)NB * K1 * 128 * 4);
  float* x2          = (float*)take((size_t)NB * K2 * 256 * 4);
  unsigned int* gbuf = (unsigned int*)take((size_t)NB * 512 * 4);
  int* ctrl          = (int*)take(128);   // [0]=q, [8..23]=ready

  hipMemsetAsync(ctrl, 0, 128, stream);

  {
    void* args[] = {
        (void*)&pos, (void*)&x, (void*)&smean, (void*)&sstd,
        (void*)&s1w1, (void*)&s1b1, (void*)&s1w2, (void*)&s1b2,
        (void*)&pxg, (void*)&pyg, (void*)&pzg,
        (void*)&d1x, (void*)&d1y, (void*)&d1z,
        (void*)&x1, (void*)&gbuf, (void*)&ctrl};
    hipLaunchCooperativeKernel((void*)phase1_kernel, dim3(256), dim3(256),
                               args, 0, stream);
  }
  hipLaunchKernelGGL(rad2conv2_kernel, dim3(NB * K2 / 4), dim3(256), 0, stream,
                     x1, d1x, d1y, d1z, s2w1, s2b1, s2w2, s2b2, x2);
  hipLaunchKernelGGL(global_sa_kernel, dim3(NB * 64), dim3(256), 0, stream,
                     x2, d1x, d1y, d1z, gw1, gb1, gw2, gb2, gbuf);
  hipLaunchKernelGGL(fc_kernel, dim3(NB), dim3(256), 0, stream,
                     gbuf, fw1, fb1, fw2, fb2, (float*)d_out);
}

// Round 16
// 1208.235 us; speedup vs baseline: 1.0364x; 1.0188x over previous
//
#include <hip/hip_runtime.h>
#include <hip/hip_bf16.h>
#include <math.h>

namespace {

constexpr int NB   = 16;     // graphs
constexpr int N1   = 4096;   // points per graph
constexpr int K1   = 1024;   // SA1 centers
constexpr int K2   = 256;    // SA2 centers (== first 256 of SA1 centers)
constexpr int MAXN = 32;     // max neighbors
constexpr int RCAP = 448;    // radius candidate capacity per wave

__device__ __forceinline__ float sigmoidf_(float x) {
  return 1.0f / (1.0f + __expf(-x));
}

__device__ __forceinline__ float readlane_f(float v, int l) {
  return __int_as_float(__builtin_amdgcn_readlane(__float_as_int(v), l));
}

// ---------------- Farthest-point sampling ----------------
// Measured-best structure (round 13): 256 threads / 4 waves, per-lane fold,
// DPP wave reduce, ping-pong LDS combine, zero global traffic in the loop,
// bulk SoA emission at the end. NEW: 2-way interleaved fold (even/odd i into
// separate accumulators, one final max) -- keys are unique so max over any
// partition = same winner, bit-exact; halves the dependent fold chain with
// no extra register moves (the round-6 tree's failure mode).
// FPS level 2 eliminated (FPS of an FPS-ordered list = its prefix, bitwise).
// Producer-consumer overlap (rounds 14/15) abandoned: consumers drop the
// chip clock ~1.5x and the serial producer eats it (574 -> 900 us).

#define FPS_DPP_STEP(CTRL)                                                     \
  {                                                                            \
    const unsigned olo =                                                       \
        (unsigned)__builtin_amdgcn_update_dpp(0, (int)lo, (CTRL), 0xF, 0xF, true); \
    const unsigned ohi =                                                       \
        (unsigned)__builtin_amdgcn_update_dpp(0, (int)hi, (CTRL), 0xF, 0xF, true); \
    const unsigned long long o = ((unsigned long long)ohi << 32) | olo;        \
    const unsigned long long cur = ((unsigned long long)hi << 32) | lo;        \
    if (o > cur) { lo = olo; hi = ohi; }                                       \
  }

template<int NPT>
__device__ __forceinline__ void fps_level(
    const float* __restrict__ sx, const float* __restrict__ sy,
    const float* __restrict__ sz, int k,
    float* __restrict__ selx, float* __restrict__ sely,
    float* __restrict__ selz,                       // LDS, length k
    unsigned long long (*red)[4]) {
  const int t = threadIdx.x;
  const int lane = t & 63, wave = t >> 6;
  float px[NPT], py[NPT], pz[NPT], mind[NPT];
  unsigned niv[NPT];
  const float c0x = sx[0], c0y = sy[0], c0z = sz[0];
  unsigned long long bestA = 0, bestB = 0;  // identity never wins
#pragma unroll
  for (int i = 0; i < NPT; i++) {
    const int p = i * 256 + t;
    niv[i] = ~(unsigned)p;
    px[i] = sx[p]; py[i] = sy[p]; pz[i] = sz[p];
    const float dx = px[i] - c0x, dy = py[i] - c0y, dz = pz[i] - c0z;
    const float d2 = dx * dx + dy * dy + dz * dz;
    mind[i] = d2;
    const unsigned long long cand =
        ((unsigned long long)__float_as_uint(d2) << 32) | niv[i];
    if (i & 1) { if (cand > bestB) bestB = cand; }
    else       { if (cand > bestA) bestA = cand; }
  }
  if (t == 0) { selx[0] = c0x; sely[0] = c0y; selz[0] = c0z; }
  for (int it = 1; it < k; it++) {
    const unsigned long long best = bestA > bestB ? bestA : bestB;
    unsigned lo = (unsigned)best, hi = (unsigned)(best >> 32);
    FPS_DPP_STEP(0x111)  // row_shr:1
    FPS_DPP_STEP(0x112)  // row_shr:2
    FPS_DPP_STEP(0x114)  // row_shr:4
    FPS_DPP_STEP(0x118)  // row_shr:8
    FPS_DPP_STEP(0x142)  // row_bcast:15
    FPS_DPP_STEP(0x143)  // row_bcast:31
    const int par = it & 1;
    if (lane == 63) red[par][wave] = ((unsigned long long)hi << 32) | lo;
    __syncthreads();
    const unsigned long long w0 = red[par][0], w1 = red[par][1];
    const unsigned long long w2 = red[par][2], w3 = red[par][3];
    const unsigned long long m01 = w0 > w1 ? w0 : w1;
    const unsigned long long m23 = w2 > w3 ? w2 : w3;
    const unsigned long long win = m01 > m23 ? m01 : m23;
    const int p = (int)(~(unsigned)win);
    const float nx = sx[p], ny = sy[p], nz = sz[p];
    if (t == 0) { selx[it] = nx; sely[it] = ny; selz[it] = nz; }
    bestA = 0; bestB = 0;
#pragma unroll
    for (int i = 0; i < NPT; i++) {
      const float dx = px[i] - nx, dy = py[i] - ny, dz = pz[i] - nz;
      const float d2 = dx * dx + dy * dy + dz * dz;
      const float m = fminf(mind[i], d2);
      mind[i] = m;
      const unsigned long long cand =
          ((unsigned long long)__float_as_uint(m) << 32) | niv[i];
      if (i & 1) { if (cand > bestB) bestB = cand; }
      else       { if (cand > bestA) bestA = cand; }
    }
  }
}

#undef FPS_DPP_STEP

// ---------------- FPS (4096 -> 1024) + SoA emission, one block/graph -------
__global__ __launch_bounds__(256) void fps_l1_kernel(
    const float* __restrict__ pos,
    float* __restrict__ pxg, float* __restrict__ pyg, float* __restrict__ pzg,
    float* __restrict__ d1x, float* __restrict__ d1y, float* __restrict__ d1z,
    unsigned int* __restrict__ gout) {
  __shared__ float sx[N1], sy[N1], sz[N1];       // 48 KiB
  __shared__ float s2x[K1], s2y[K1], s2z[K1];    // 12 KiB (selections)
  __shared__ __align__(16) unsigned long long red[2][4];
  const int b = blockIdx.x;
  const int t = threadIdx.x;
  // zero-init the global-SA atomicMax buffer (replaces a memset launch)
  gout[b * 512 + t] = 0u;
  gout[b * 512 + t + 256] = 0u;
  const float* pb = pos + (size_t)b * N1 * 3;
  for (int p = t; p < N1; p += 256) {
    sx[p] = pb[p * 3 + 0]; sy[p] = pb[p * 3 + 1]; sz[p] = pb[p * 3 + 2];
  }
  __syncthreads();
  fps_level<N1 / 256>(sx, sy, sz, K1, s2x, s2y, s2z, red);
  __syncthreads();
  // SoA copy of all positions (coalesced) for the radius/conv consumers
  for (int p = t; p < N1; p += 256) {
    pxg[(size_t)b * N1 + p] = sx[p];
    pyg[(size_t)b * N1 + p] = sy[p];
    pzg[(size_t)b * N1 + p] = sz[p];
  }
  // SoA center list (coalesced)
  for (int i = t; i < K1; i += 256) {
    d1x[(size_t)b * K1 + i] = s2x[i];
    d1y[(size_t)b * K1 + i] = s2y[i];
    d1z[(size_t)b * K1 + i] = s2z[i];
  }
}

// ---------------- radius + 32 nearest -> LDS lists (per wave) ----------
struct RadSmem {
  float candd[4][RCAP];
  int   candi[4][RCAP];
};

__device__ __forceinline__ void radius_lds(
    const float* __restrict__ px, const float* __restrict__ py,
    const float* __restrict__ pz, int N,
    float cx, float cy, float cz, float r2,
    RadSmem& sm, int* nb, int* cntp, int wave, int lane) {
  int total = 0;
  for (int base = 0; base < N; base += 64) {
    const int p = base + lane;
    const float dx = px[p] - cx;
    const float dy = py[p] - cy;
    const float dz = pz[p] - cz;
    const float d2 = dx * dx + dy * dy + dz * dz;
    const bool pred = d2 <= r2;
    const unsigned long long m = __ballot(pred);
    if (pred) {
      const int slot = total + __popcll(m & ((1ull << lane) - 1ull));
      if (slot < RCAP) { sm.candd[wave][slot] = d2; sm.candi[wave][slot] = p; }
    }
    total += __popcll(m);
  }
  if (total > RCAP) total = RCAP;
  if (total <= MAXN) {
    if (lane < total) nb[lane] = sm.candi[wave][lane];
  } else {
    for (int jj = 0; jj < MAXN; jj++) {
      float bvd = INFINITY; int bvi = 0x7fffffff; int bslot = 0;
      for (int s = lane; s < total; s += 64) {
        const float d = sm.candd[wave][s];
        const int i = sm.candi[wave][s];
        if (d < bvd || (d == bvd && i < bvi)) { bvd = d; bvi = i; bslot = s; }
      }
#pragma unroll
      for (int off = 32; off; off >>= 1) {
        const float od = __shfl_xor(bvd, off);
        const int   oi = __shfl_xor(bvi, off);
        const int   os = __shfl_xor(bslot, off);
        if (od < bvd || (od == bvd && oi < bvi)) { bvd = od; bvi = oi; bslot = os; }
      }
      if (lane == 0) { nb[jj] = bvi; sm.candd[wave][bslot] = INFINITY; }
    }
  }
  if (lane == 0) *cntp = (total < MAXN) ? total : MAXN;
}

// ---------------- PointNetConv edge MLP + max agg (one center) ----------
// Rows-in-lanes + readlane broadcast; vectorized weight streaming
// (round-11 verified scalar-fma form). nb/V come from LDS.
template<int CIN_T, int H, int COUT, bool SCALE>
__device__ __forceinline__ void conv_center(
    const float* __restrict__ xin,   // graph base [N][CIN_T]
    const float* __restrict__ ptsx, const float* __restrict__ ptsy,
    const float* __restrict__ ptsz,  // graph base [N]
    float ctrx, float ctry, float ctrz,
    const int* nb, int V,
    const float* __restrict__ w1, const float* __restrict__ b1,
    const float* __restrict__ w2, const float* __restrict__ b2,
    const float* __restrict__ smean, const float* __restrict__ sstd,
    float* __restrict__ outrow, float* part /* LDS [4*COUT] */) {
  constexpr int FIN  = CIN_T + 3;
  constexpr int KREG = (FIN + 63) / 64;
  constexpr int HREG = H / 64;            // h = lane*HREG + q
  constexpr int CREG = COUT / 64;         // c = lane*CREG + q
  constexpr int RPW  = MAXN / 4;
  const int t = threadIdx.x, lane = t & 63, wave = t >> 6;
  float m[CREG];
#pragma unroll
  for (int ck = 0; ck < CREG; ck++) m[ck] = -INFINITY;
  if (V > wave * RPW) {
    float sm = 0.0f, sd = 1.0f;
    if (SCALE && lane < CIN_T) { sm = smean[lane]; sd = sstd[lane]; }
    float fr[RPW][KREG];
#pragma unroll
    for (int r = 0; r < RPW; r++) {
      const int j = wave * RPW + r;
      const int p = (j < V) ? nb[j] : nb[0];
#pragma unroll
      for (int k2 = 0; k2 < KREG; k2++) {
        const int f = k2 * 64 + lane;
        float v = 0.0f;
        if (f < CIN_T) {
          v = xin[(size_t)p * CIN_T + f];
          if constexpr (SCALE) v = (v - sm) / sd;
        } else if (f < FIN) {
          const int d = f - CIN_T;
          const float pv = (d == 0 ? ptsx : (d == 1 ? ptsy : ptsz))[p];
          v = pv - (d == 0 ? ctrx : (d == 1 ? ctry : ctrz));
        }
        fr[r][k2] = v;
      }
    }
    float hh[RPW][HREG];
    {
      float acc[RPW][HREG];
#pragma unroll
      for (int r = 0; r < RPW; r++)
#pragma unroll
        for (int q = 0; q < HREG; q++) acc[r][q] = 0.0f;
#pragma unroll
      for (int k2 = 0; k2 < KREG; k2++) {
        const int lim = (FIN - k2 * 64) < 64 ? (FIN - k2 * 64) : 64;
        for (int fl = 0; fl < lim; fl++) {     // f ascending
          const int f = k2 * 64 + fl;
          float wv[HREG];
          if constexpr (HREG == 1) {
            wv[0] = w1[(size_t)f * H + lane];
          } else {
            const float2 w = *reinterpret_cast<const float2*>(
                &w1[(size_t)f * H + lane * 2]);
            wv[0] = w.x; wv[1] = w.y;
          }
#pragma unroll
          for (int r = 0; r < RPW; r++) {
            const float s = readlane_f(fr[r][k2], fl);
#pragma unroll
            for (int q = 0; q < HREG; q++) acc[r][q] = fmaf(s, wv[q], acc[r][q]);
          }
        }
      }
#pragma unroll
      for (int q = 0; q < HREG; q++) {
        const float bb = b1[lane * HREG + q];
#pragma unroll
        for (int r = 0; r < RPW; r++) hh[r][q] = sigmoidf_(acc[r][q] + bb);
      }
    }
    float acc2[RPW][CREG];
#pragma unroll
    for (int r = 0; r < RPW; r++)
#pragma unroll
      for (int q = 0; q < CREG; q++) acc2[r][q] = 0.0f;
    for (int hl = 0; hl < 64; hl++) {
#pragma unroll
      for (int q1 = 0; q1 < HREG; q1++) {
        const int h = hl * HREG + q1;
        float wv[CREG];
        if constexpr (CREG == 2) {
          const float2 w = *reinterpret_cast<const float2*>(
              &w2[(size_t)h * COUT + lane * 2]);
          wv[0] = w.x; wv[1] = w.y;
        } else {
          const float4 w = *reinterpret_cast<const float4*>(
              &w2[(size_t)h * COUT + lane * 4]);
          wv[0] = w.x; wv[1] = w.y; wv[2] = w.z; wv[3] = w.w;
        }
#pragma unroll
        for (int r = 0; r < RPW; r++) {
          const float s = readlane_f(hh[r][q1], hl);
#pragma unroll
          for (int q = 0; q < CREG; q++) acc2[r][q] = fmaf(s, wv[q], acc2[r][q]);
        }
      }
    }
#pragma unroll
    for (int r = 0; r < RPW; r++) {
      if (wave * RPW + r < V) {
#pragma unroll
        for (int q = 0; q < CREG; q++) m[q] = fmaxf(m[q], acc2[r][q]);
      }
    }
  }
#pragma unroll
  for (int q = 0; q < CREG; q++) part[wave * COUT + lane * CREG + q] = m[q];
  __syncthreads();
  if (t < COUT) {
    const float mm = fmaxf(fmaxf(part[0 * COUT + t], part[1 * COUT + t]),
                           fmaxf(part[2 * COUT + t], part[3 * COUT + t]));
    const float o = mm + b2[t];
    outrow[t] = o > 0.0f ? o : 0.0f;
  }
}

// ---------------- Fused radius1 + conv1: one block per 4 centers ----------
__global__ __launch_bounds__(256) void rad1conv1_kernel(
    const float* __restrict__ x,
    const float* __restrict__ pxg, const float* __restrict__ pyg,
    const float* __restrict__ pzg,
    const float* __restrict__ d1x, const float* __restrict__ d1y,
    const float* __restrict__ d1z,
    const float* __restrict__ s1w1, const float* __restrict__ s1b1,
    const float* __restrict__ s1w2, const float* __restrict__ s1b2,
    const float* __restrict__ smean, const float* __restrict__ sstd,
    float* __restrict__ x1) {
  __shared__ __align__(16) RadSmem rs;
  __shared__ int nb_l[4 * MAXN];
  __shared__ int cnt_l[4];
  __shared__ __align__(16) float part[4 * 128];
  const int t = threadIdx.x, lane = t & 63, wave = t >> 6;
  const int b = blockIdx.x / (K1 / 4), grp = blockIdx.x % (K1 / 4);
  const size_t pB = (size_t)b * N1, cB = (size_t)b * K1;
  const int ci = 4 * grp + wave;
  radius_lds(pxg + pB, pyg + pB, pzg + pB, N1,
             d1x[cB + ci], d1y[cB + ci], d1z[cB + ci], 4.0f,
             rs, nb_l + wave * MAXN, &cnt_l[wave], wave, lane);
  __syncthreads();
  for (int cc = 0; cc < 4; cc++) {
    const int c2 = 4 * grp + cc;
    conv_center<32, 64, 128, true>(
        x + pB * 32, pxg + pB, pyg + pB, pzg + pB,
        d1x[cB + c2], d1y[cB + c2], d1z[cB + c2],
        nb_l + cc * MAXN, cnt_l[cc],
        s1w1, s1b1, s1w2, s1b2, smean, sstd,
        x1 + (cB + c2) * 128, part);
    __syncthreads();
  }
}

// ---------------- Fused radius2 + conv2: one block per 4 centers ----------
__global__ __launch_bounds__(256) void rad2conv2_kernel(
    const float* __restrict__ x1,
    const float* __restrict__ d1x, const float* __restrict__ d1y,
    const float* __restrict__ d1z,
    const float* __restrict__ s2w1, const float* __restrict__ s2b1,
    const float* __restrict__ s2w2, const float* __restrict__ s2b2,
    float* __restrict__ x2) {
  __shared__ __align__(16) RadSmem rs;
  __shared__ int nb_l[4 * MAXN];
  __shared__ int cnt_l[4];
  __shared__ __align__(16) float part[4 * 256];
  const int t = threadIdx.x, lane = t & 63, wave = t >> 6;
  const int b = blockIdx.x / (K2 / 4), grp = blockIdx.x % (K2 / 4);
  const size_t cB = (size_t)b * K1;
  const int ci = 4 * grp + wave;
  radius_lds(d1x + cB, d1y + cB, d1z + cB, K1,
             d1x[cB + ci], d1y[cB + ci], d1z[cB + ci], 16.0f,
             rs, nb_l + wave * MAXN, &cnt_l[wave], wave, lane);
  __syncthreads();
  for (int cc = 0; cc < 4; cc++) {
    const int c2 = 4 * grp + cc;
    conv_center<128, 128, 256, false>(
        x1 + cB * 128, d1x + cB, d1y + cB, d1z + cB,
        d1x[cB + c2], d1y[cB + c2], d1z[cB + c2],
        nb_l + cc * MAXN, cnt_l[cc],
        s2w1, s2b1, s2w2, s2b2, nullptr, nullptr,
        x2 + ((size_t)b * K2 + c2) * 256, part);
    __syncthreads();
  }
}

// ---------------- Global SA: MLP(259->256->512) + relu + max pool ----------
__global__ __launch_bounds__(256) void global_sa_kernel(
    const float* __restrict__ x2,
    const float* __restrict__ d1x, const float* __restrict__ d1y,
    const float* __restrict__ d1z,
    const float* __restrict__ gw1, const float* __restrict__ gb1,
    const float* __restrict__ gw2, const float* __restrict__ gb2,
    unsigned int* __restrict__ gout) {  // [B][512] as float bits (relu >= 0)
  __shared__ float fin[4][259];
  __shared__ float s[4][256];
  const int t = threadIdx.x;
  const int blk = blockIdx.x;
  const int b = blk / 64;
  const int p0 = (blk % 64) * 4;
  for (int item = t; item < 4 * 259; item += 256) {
    const int p = item / 259, f = item - p * 259;
    float v;
    if (f < 256) {
      v = x2[((size_t)b * 256 + p0 + p) * 256 + f];
    } else {
      const int d = f - 256;
      v = (d == 0 ? d1x : (d == 1 ? d1y : d1z))[(size_t)b * K1 + p0 + p];
    }
    fin[p][f] = v;
  }
  __syncthreads();
  float acc[4] = {0.f, 0.f, 0.f, 0.f};
  for (int f = 0; f < 259; f++) {
    const float w = gw1[f * 256 + t];
#pragma unroll
    for (int p = 0; p < 4; p++) acc[p] = fmaf(fin[p][f], w, acc[p]);
  }
  const float bb = gb1[t];
#pragma unroll
  for (int p = 0; p < 4; p++) s[p][t] = sigmoidf_(acc[p] + bb);
  __syncthreads();
  float a0[4] = {0.f, 0.f, 0.f, 0.f}, a1[4] = {0.f, 0.f, 0.f, 0.f};
  for (int h = 0; h < 256; h++) {
    const float w0 = gw2[h * 512 + t];
    const float w1v = gw2[h * 512 + t + 256];
#pragma unroll
    for (int p = 0; p < 4; p++) {
      a0[p] = fmaf(s[p][h], w0, a0[p]);
      a1[p] = fmaf(s[p][h], w1v, a1[p]);
    }
  }
  const float b0 = gb2[t], b1v = gb2[t + 256];
  float m0 = 0.0f, m1 = 0.0f;  // relu floor
#pragma unroll
  for (int p = 0; p < 4; p++) {
    m0 = fmaxf(m0, fmaxf(a0[p] + b0, 0.0f));
    m1 = fmaxf(m1, fmaxf(a1[p] + b1v, 0.0f));
  }
  atomicMax(&gout[b * 512 + t], __float_as_uint(m0));
  atomicMax(&gout[b * 512 + t + 256], __float_as_uint(m1));
}

// ---------------- Final FC head (float32 output) ----------------
__global__ __launch_bounds__(256) void fc_kernel(
    const unsigned int* __restrict__ g,
    const float* __restrict__ fw1, const float* __restrict__ fb1,
    const float* __restrict__ fw2, const float* __restrict__ fb2,
    float* __restrict__ out) {
  __shared__ float gv[512];
  __shared__ float s[256];
  const int b = blockIdx.x, t = threadIdx.x;
  gv[t] = __uint_as_float(g[b * 512 + t]);
  gv[t + 256] = __uint_as_float(g[b * 512 + t + 256]);
  __syncthreads();
  float acc = 0.0f;
  for (int h = 0; h < 512; h++) acc = fmaf(gv[h], fw1[h * 256 + t], acc);
  s[t] = sigmoidf_(acc + fb1[t]);
  __syncthreads();
  if (t < 128) {
    float a2 = 0.0f;
    for (int h = 0; h < 256; h++) a2 = fmaf(s[h], fw2[h * 128 + t], a2);
    const float o = a2 + fb2[t];
    out[b * 128 + t] = o > 0.0f ? o : 0.0f;
  }
}

}  // namespace

extern "C" void kernel_launch(void* const* d_in, const int* in_sizes, int n_in,
                              void* d_out, int out_size, void* d_ws, size_t ws_size,
                              hipStream_t stream) {
  (void)in_sizes; (void)n_in; (void)out_size; (void)ws_size;
  const float* x     = (const float*)d_in[0];
  const float* pos   = (const float*)d_in[1];
  // d_in[2] = batch (int64) — sorted, equal-sized graphs, unused
  const float* smean = (const float*)d_in[3];
  const float* sstd  = (const float*)d_in[4];
  const float* s1w1  = (const float*)d_in[5];
  const float* s1b1  = (const float*)d_in[6];
  const float* s1w2  = (const float*)d_in[7];
  const float* s1b2  = (const float*)d_in[8];
  const float* s2w1  = (const float*)d_in[9];
  const float* s2b1  = (const float*)d_in[10];
  const float* s2w2  = (const float*)d_in[11];
  const float* s2b2  = (const float*)d_in[12];
  const float* gw1   = (const float*)d_in[13];
  const float* gb1   = (const float*)d_in[14];
  const float* gw2   = (const float*)d_in[15];
  const float* gb2   = (const float*)d_in[16];
  const float* fw1   = (const float*)d_in[17];
  const float* fb1   = (const float*)d_in[18];
  const float* fw2   = (const float*)d_in[19];
  const float* fb2   = (const float*)d_in[20];

  char* ws = (char*)d_ws;
  size_t off = 0;
  auto take = [&](size_t bytes) -> char* {
    char* p = ws + off;
    off = (off + bytes + 255) & ~(size_t)255;
    return p;
  };
  float* pxg         = (float*)take((size_t)NB * N1 * 4);
  float* pyg         = (float*)take((size_t)NB * N1 * 4);
  float* pzg         = (float*)take((size_t)NB * N1 * 4);
  float* d1x         = (float*)take((size_t)NB * K1 * 4);
  float* d1y         = (float*)take((size_t)NB * K1 * 4);
  float* d1z         = (float*)take((size_t)NB * K1 * 4);
  float* x1          = (float*)take((size_t)NB * K1 * 128 * 4);
  float* x2          = (float*)take((size_t)NB * K2 * 256 * 4);
  unsigned int* gbuf = (unsigned int*)take((size_t)NB * 512 * 4);

  hipLaunchKernelGGL(fps_l1_kernel, dim3(NB), dim3(256), 0, stream,
                     pos, pxg, pyg, pzg, d1x, d1y, d1z, gbuf);
  hipLaunchKernelGGL(rad1conv1_kernel, dim3(NB * K1 / 4), dim3(256), 0, stream,
                     x, pxg, pyg, pzg, d1x, d1y, d1z,
                     s1w1, s1b1, s1w2, s1b2, smean, sstd, x1);
  hipLaunchKernelGGL(rad2conv2_kernel, dim3(NB * K2 / 4), dim3(256), 0, stream,
                     x1, d1x, d1y, d1z, s2w1, s2b1, s2w2, s2b2, x2);
  hipLaunchKernelGGL(global_sa_kernel, dim3(NB * 64), dim3(256), 0, stream,
                     x2, d1x, d1y, d1z, gw1, gb1, gw2, gb2, gbuf);
  hipLaunchKernelGGL(fc_kernel, dim3(NB), dim3(256), 0, stream,
                     gbuf, fw1, fb1, fw2, fb2, (float*)d_out);
}

// Round 17
// 1150.023 us; speedup vs baseline: 1.0889x; 1.0506x over previous
//
#include <hip/hip_runtime.h>
#include <hip/hip_bf16.h>
#include <math.h>

namespace {

constexpr int NB   = 16;     // graphs
constexpr int N1   = 4096;   // points per graph
constexpr int K1   = 1024;   // SA1 centers
constexpr int K2   = 256;    // SA2 centers (== first 256 of SA1 centers)
constexpr int MAXN = 32;     // max neighbors
constexpr int RCAP = 448;    // radius candidate capacity per wave

__device__ __forceinline__ float sigmoidf_(float x) {
  return 1.0f / (1.0f + __expf(-x));
}

__device__ __forceinline__ float readlane_f(float v, int l) {
  return __int_as_float(__builtin_amdgcn_readlane(__float_as_int(v), l));
}

// ---------------- Farthest-point sampling ----------------
// Measured-best structure (round 13, 574 us): 256 threads / 4 waves, serial
// per-lane u64-key fold, DPP wave reduce, ping-pong LDS combine, zero global
// traffic in the loop, bulk SoA emission at the end.
// Keys: (f32 dist bits << 32) | ~idx so one u64 max = "max dist, tie ->
// smallest index" (jnp.argmax first-occurrence).
// FPS level 2 eliminated (FPS of an FPS-ordered list = its prefix, bitwise).
// Bracketed-floor: tree fold, 8-wave, pk-math, interleaved fold, in-loop
// global stores, and producer-consumer overlap (DVFS throttle) all regressed.

#define FPS_DPP_STEP(CTRL)                                                     \
  {                                                                            \
    const unsigned olo =                                                       \
        (unsigned)__builtin_amdgcn_update_dpp(0, (int)lo, (CTRL), 0xF, 0xF, true); \
    const unsigned ohi =                                                       \
        (unsigned)__builtin_amdgcn_update_dpp(0, (int)hi, (CTRL), 0xF, 0xF, true); \
    const unsigned long long o = ((unsigned long long)ohi << 32) | olo;        \
    const unsigned long long cur = ((unsigned long long)hi << 32) | lo;        \
    if (o > cur) { lo = olo; hi = ohi; }                                       \
  }

template<int NPT>
__device__ __forceinline__ void fps_level(
    const float* __restrict__ sx, const float* __restrict__ sy,
    const float* __restrict__ sz, int k,
    float* __restrict__ selx, float* __restrict__ sely,
    float* __restrict__ selz,                       // LDS, length k
    unsigned long long (*red)[4]) {
  const int t = threadIdx.x;
  const int lane = t & 63, wave = t >> 6;
  float px[NPT], py[NPT], pz[NPT], mind[NPT];
  unsigned niv[NPT];
  const float c0x = sx[0], c0y = sy[0], c0z = sz[0];
  unsigned long long best = 0;  // identity: dist 0, idx ~0 (never wins)
#pragma unroll
  for (int i = 0; i < NPT; i++) {
    const int p = i * 256 + t;
    niv[i] = ~(unsigned)p;
    px[i] = sx[p]; py[i] = sy[p]; pz[i] = sz[p];
    const float dx = px[i] - c0x, dy = py[i] - c0y, dz = pz[i] - c0z;
    const float d2 = dx * dx + dy * dy + dz * dz;
    mind[i] = d2;
    const unsigned long long cand =
        ((unsigned long long)__float_as_uint(d2) << 32) | niv[i];
    if (cand > best) best = cand;
  }
  if (t == 0) { selx[0] = c0x; sely[0] = c0y; selz[0] = c0z; }
  for (int it = 1; it < k; it++) {
    unsigned lo = (unsigned)best, hi = (unsigned)(best >> 32);
    FPS_DPP_STEP(0x111)  // row_shr:1
    FPS_DPP_STEP(0x112)  // row_shr:2
    FPS_DPP_STEP(0x114)  // row_shr:4
    FPS_DPP_STEP(0x118)  // row_shr:8
    FPS_DPP_STEP(0x142)  // row_bcast:15
    FPS_DPP_STEP(0x143)  // row_bcast:31
    const int par = it & 1;
    if (lane == 63) red[par][wave] = ((unsigned long long)hi << 32) | lo;
    __syncthreads();
    const unsigned long long w0 = red[par][0], w1 = red[par][1];
    const unsigned long long w2 = red[par][2], w3 = red[par][3];
    const unsigned long long m01 = w0 > w1 ? w0 : w1;
    const unsigned long long m23 = w2 > w3 ? w2 : w3;
    const unsigned long long win = m01 > m23 ? m01 : m23;
    const int p = (int)(~(unsigned)win);
    const float nx = sx[p], ny = sy[p], nz = sz[p];
    if (t == 0) { selx[it] = nx; sely[it] = ny; selz[it] = nz; }
    best = 0;
#pragma unroll
    for (int i = 0; i < NPT; i++) {
      const float dx = px[i] - nx, dy = py[i] - ny, dz = pz[i] - nz;
      const float d2 = dx * dx + dy * dy + dz * dz;
      const float m = fminf(mind[i], d2);
      mind[i] = m;
      const unsigned long long cand =
          ((unsigned long long)__float_as_uint(m) << 32) | niv[i];
      if (cand > best) best = cand;
    }
  }
}

#undef FPS_DPP_STEP

// ---------------- FPS (4096 -> 1024) + SoA emission, one block/graph -------
__global__ __launch_bounds__(256) void fps_l1_kernel(
    const float* __restrict__ pos,
    float* __restrict__ pxg, float* __restrict__ pyg, float* __restrict__ pzg,
    float* __restrict__ d1x, float* __restrict__ d1y, float* __restrict__ d1z,
    unsigned int* __restrict__ gout) {
  __shared__ float sx[N1], sy[N1], sz[N1];       // 48 KiB
  __shared__ float s2x[K1], s2y[K1], s2z[K1];    // 12 KiB (selections)
  __shared__ __align__(16) unsigned long long red[2][4];
  const int b = blockIdx.x;
  const int t = threadIdx.x;
  // zero-init the global-SA atomicMax buffer (replaces a memset launch)
  gout[b * 512 + t] = 0u;
  gout[b * 512 + t + 256] = 0u;
  const float* pb = pos + (size_t)b * N1 * 3;
  for (int p = t; p < N1; p += 256) {
    sx[p] = pb[p * 3 + 0]; sy[p] = pb[p * 3 + 1]; sz[p] = pb[p * 3 + 2];
  }
  __syncthreads();
  fps_level<N1 / 256>(sx, sy, sz, K1, s2x, s2y, s2z, red);
  __syncthreads();
  // SoA copy of all positions (coalesced) for the radius/conv consumers
  for (int p = t; p < N1; p += 256) {
    pxg[(size_t)b * N1 + p] = sx[p];
    pyg[(size_t)b * N1 + p] = sy[p];
    pzg[(size_t)b * N1 + p] = sz[p];
  }
  // SoA center list (coalesced)
  for (int i = t; i < K1; i += 256) {
    d1x[(size_t)b * K1 + i] = s2x[i];
    d1y[(size_t)b * K1 + i] = s2y[i];
    d1z[(size_t)b * K1 + i] = s2z[i];
  }
}

// ---------------- radius + 32 nearest (SoA reads) ----------------
struct RadSmem {
  float candd[4][RCAP];
  int   candi[4][RCAP];
};

__device__ __forceinline__ void radius_body(
    const float* __restrict__ ptsx, const float* __restrict__ ptsy,
    const float* __restrict__ ptsz, int N,
    const float* __restrict__ cxs, const float* __restrict__ cys,
    const float* __restrict__ czs, int K, int CSTR, float r2,
    int* __restrict__ nbr, int* __restrict__ cnt_out, RadSmem& sm, int rb) {
  const int t = threadIdx.x;
  const int lane = t & 63, wave = t >> 6;
  const int bpg = K / 4;
  const int b = rb / bpg;
  const int ci = (rb % bpg) * 4 + wave;
  const size_t pbase = (size_t)b * N;
  const size_t cbase = (size_t)b * CSTR + ci;
  const float cx = cxs[cbase], cy = cys[cbase], cz = czs[cbase];
  int total = 0;
  for (int base = 0; base < N; base += 64) {
    const int p = base + lane;
    const float dx = ptsx[pbase + p] - cx;
    const float dy = ptsy[pbase + p] - cy;
    const float dz = ptsz[pbase + p] - cz;
    const float d2 = dx * dx + dy * dy + dz * dz;
    const bool pred = d2 <= r2;
    const unsigned long long m = __ballot(pred);
    if (pred) {
      const int slot = total + __popcll(m & ((1ull << lane) - 1ull));
      if (slot < RCAP) { sm.candd[wave][slot] = d2; sm.candi[wave][slot] = p; }
    }
    total += __popcll(m);
  }
  if (total > RCAP) total = RCAP;
  int* nbp = nbr + ((size_t)b * K + ci) * MAXN;
  if (total <= MAXN) {
    if (lane < total) nbp[lane] = sm.candi[wave][lane];
  } else {
    for (int jj = 0; jj < MAXN; jj++) {
      float bvd = INFINITY; int bvi = 0x7fffffff; int bslot = 0;
      for (int s = lane; s < total; s += 64) {
        const float d = sm.candd[wave][s];
        const int i = sm.candi[wave][s];
        if (d < bvd || (d == bvd && i < bvi)) { bvd = d; bvi = i; bslot = s; }
      }
#pragma unroll
      for (int off = 32; off; off >>= 1) {
        const float od = __shfl_xor(bvd, off);
        const int   oi = __shfl_xor(bvi, off);
        const int   os = __shfl_xor(bslot, off);
        if (od < bvd || (od == bvd && oi < bvi)) { bvd = od; bvi = oi; bslot = os; }
      }
      if (lane == 0) { nbp[jj] = bvi; sm.candd[wave][bslot] = INFINITY; }
    }
  }
  if (lane == 0) cnt_out[(size_t)b * K + ci] = (total < MAXN) ? total : MAXN;
}

// merged radius1 (blocks 0..NB*K1/4-1) | radius2 (rest)
__global__ __launch_bounds__(256) void rad12_kernel(
    const float* __restrict__ pxg, const float* __restrict__ pyg,
    const float* __restrict__ pzg,
    const float* __restrict__ d1x, const float* __restrict__ d1y,
    const float* __restrict__ d1z,
    int* __restrict__ nbr1, int* __restrict__ cnt1,
    int* __restrict__ nbr2, int* __restrict__ cnt2) {
  constexpr int NR1 = NB * K1 / 4;
  __shared__ __align__(16) RadSmem r;
  if (blockIdx.x < (unsigned)NR1) {
    radius_body(pxg, pyg, pzg, N1, d1x, d1y, d1z, K1, K1, 4.0f,
                nbr1, cnt1, r, blockIdx.x);
  } else {
    radius_body(d1x, d1y, d1z, K1, d1x, d1y, d1z, K2, K1, 16.0f,
                nbr2, cnt2, r, blockIdx.x - NR1);
  }
}

// ---------------- PointNetConv edge MLP + max aggregation ----------------
// Rows-in-lanes + readlane broadcast; vectorized weight streaming (round-11
// verified scalar-fma form; pk_fma spilled to scratch and regressed).
template<int CIN_T, int H, int COUT, bool SCALE>
__device__ __forceinline__ void sa_conv_body(
    const float* __restrict__ xin,
    const float* __restrict__ ptsx, const float* __restrict__ ptsy,
    const float* __restrict__ ptsz,
    const float* __restrict__ cxs, const float* __restrict__ cys,
    const float* __restrict__ czs,
    const int* __restrict__ nbr, const int* __restrict__ cnt,
    const float* __restrict__ w1, const float* __restrict__ b1,
    const float* __restrict__ w2, const float* __restrict__ b2,
    const float* __restrict__ smean, const float* __restrict__ sstd,
    int N, int K, int CSTR, float* __restrict__ xout,
    float* part /* LDS [4*COUT] */, int bk) {
  constexpr int FIN  = CIN_T + 3;
  constexpr int KREG = (FIN + 63) / 64;   // feat regs per row per lane
  constexpr int HREG = H / 64;            // hidden regs: h = lane*HREG + q
  constexpr int CREG = COUT / 64;         // out regs:    c = lane*CREG + q
  constexpr int RPW  = MAXN / 4;          // 8 rows per wave
  const int t = threadIdx.x, lane = t & 63, wave = t >> 6;
  const int b = bk / K;
  const int V = cnt[bk];
  float m[CREG];
#pragma unroll
  for (int ck = 0; ck < CREG; ck++) m[ck] = -INFINITY;
  if (V > wave * RPW) {  // wave-uniform: skip waves with no valid rows
    const int* nb = nbr + (size_t)bk * MAXN;
    const size_t crow = (size_t)b * CSTR + (bk - b * K);
    const float ctrx = cxs[crow];
    const float ctry = cys[crow];
    const float ctrz = czs[crow];
    float sm = 0.0f, sd = 1.0f;
    if (SCALE && lane < CIN_T) { sm = smean[lane]; sd = sstd[lane]; }
    float fr[RPW][KREG];
#pragma unroll
    for (int r = 0; r < RPW; r++) {
      const int j = wave * RPW + r;
      const int p = (j < V) ? nb[j] : nb[0];
#pragma unroll
      for (int k2 = 0; k2 < KREG; k2++) {
        const int f = k2 * 64 + lane;
        float v = 0.0f;
        if (f < CIN_T) {
          v = xin[((size_t)b * N + p) * CIN_T + f];
          if constexpr (SCALE) v = (v - sm) / sd;
        } else if (f < FIN) {
          const int d = f - CIN_T;
          const float pv = (d == 0 ? ptsx : (d == 1 ? ptsy : ptsz))[(size_t)b * N + p];
          v = pv - (d == 0 ? ctrx : (d == 1 ? ctry : ctrz));
        }
        fr[r][k2] = v;
      }
    }
    // ---- layer 1 ----
    float hh[RPW][HREG];
    {
      float acc[RPW][HREG];
#pragma unroll
      for (int r = 0; r < RPW; r++)
#pragma unroll
        for (int q = 0; q < HREG; q++) acc[r][q] = 0.0f;
#pragma unroll
      for (int k2 = 0; k2 < KREG; k2++) {
        const int lim = (FIN - k2 * 64) < 64 ? (FIN - k2 * 64) : 64;
        for (int fl = 0; fl < lim; fl++) {     // f ascending
          const int f = k2 * 64 + fl;
          float wv[HREG];
          if constexpr (HREG == 1) {
            wv[0] = w1[(size_t)f * H + lane];
          } else {
            const float2 w = *reinterpret_cast<const float2*>(
                &w1[(size_t)f * H + lane * 2]);
            wv[0] = w.x; wv[1] = w.y;
          }
#pragma unroll
          for (int r = 0; r < RPW; r++) {
            const float s = readlane_f(fr[r][k2], fl);
#pragma unroll
            for (int q = 0; q < HREG; q++) acc[r][q] = fmaf(s, wv[q], acc[r][q]);
          }
        }
      }
#pragma unroll
      for (int q = 0; q < HREG; q++) {
        const float bb = b1[lane * HREG + q];
#pragma unroll
        for (int r = 0; r < RPW; r++) hh[r][q] = sigmoidf_(acc[r][q] + bb);
      }
    }
    // ---- layer 2 (h = hl*HREG + q1 enumerated ascending) ----
    float acc2[RPW][CREG];
#pragma unroll
    for (int r = 0; r < RPW; r++)
#pragma unroll
      for (int q = 0; q < CREG; q++) acc2[r][q] = 0.0f;
    for (int hl = 0; hl < 64; hl++) {
#pragma unroll
      for (int q1 = 0; q1 < HREG; q1++) {
        const int h = hl * HREG + q1;
        float wv[CREG];
        if constexpr (CREG == 2) {
          const float2 w = *reinterpret_cast<const float2*>(
              &w2[(size_t)h * COUT + lane * 2]);
          wv[0] = w.x; wv[1] = w.y;
        } else {
          const float4 w = *reinterpret_cast<const float4*>(
              &w2[(size_t)h * COUT + lane * 4]);
          wv[0] = w.x; wv[1] = w.y; wv[2] = w.z; wv[3] = w.w;
        }
#pragma unroll
        for (int r = 0; r < RPW; r++) {
          const float s = readlane_f(hh[r][q1], hl);
#pragma unroll
          for (int q = 0; q < CREG; q++) acc2[r][q] = fmaf(s, wv[q], acc2[r][q]);
        }
      }
    }
#pragma unroll
    for (int r = 0; r < RPW; r++) {
      if (wave * RPW + r < V) {
#pragma unroll
        for (int q = 0; q < CREG; q++) m[q] = fmaxf(m[q], acc2[r][q]);
      }
    }
  }
#pragma unroll
  for (int q = 0; q < CREG; q++) part[wave * COUT + lane * CREG + q] = m[q];
  __syncthreads();
  if (t < COUT) {
    const float mm = fmaxf(fmaxf(part[0 * COUT + t], part[1 * COUT + t]),
                           fmaxf(part[2 * COUT + t], part[3 * COUT + t]));
    const float o = mm + b2[t];
    xout[(size_t)bk * COUT + t] = o > 0.0f ? o : 0.0f;
  }
}

__global__ __launch_bounds__(256) void conv1_kernel(
    const float* __restrict__ x,
    const float* __restrict__ pxg, const float* __restrict__ pyg,
    const float* __restrict__ pzg,
    const float* __restrict__ d1x, const float* __restrict__ d1y,
    const float* __restrict__ d1z,
    const int* __restrict__ nbr1, const int* __restrict__ cnt1,
    const float* __restrict__ s1w1, const float* __restrict__ s1b1,
    const float* __restrict__ s1w2, const float* __restrict__ s1b2,
    const float* __restrict__ smean, const float* __restrict__ sstd,
    float* __restrict__ x1) {
  __shared__ __align__(16) float part[4 * 128];
  sa_conv_body<32, 64, 128, true>(x, pxg, pyg, pzg, d1x, d1y, d1z,
                                  nbr1, cnt1, s1w1, s1b1, s1w2, s1b2,
                                  smean, sstd, N1, K1, K1, x1, part,
                                  blockIdx.x);
}

__global__ __launch_bounds__(256) void conv2_kernel(
    const float* __restrict__ x1,
    const float* __restrict__ d1x, const float* __restrict__ d1y,
    const float* __restrict__ d1z,
    const int* __restrict__ nbr2, const int* __restrict__ cnt2,
    const float* __restrict__ s2w1, const float* __restrict__ s2b1,
    const float* __restrict__ s2w2, const float* __restrict__ s2b2,
    float* __restrict__ x2) {
  __shared__ __align__(16) float part[4 * 256];
  // points AND centers = posd1 (centers are its first K2 rows per graph)
  sa_conv_body<128, 128, 256, false>(x1, d1x, d1y, d1z, d1x, d1y, d1z,
                                     nbr2, cnt2, s2w1, s2b1, s2w2, s2b2,
                                     nullptr, nullptr, K1, K2, K1, x2, part,
                                     blockIdx.x);
}

// ---------------- Global SA: MLP(259->256->512) + relu + max pool ----------
__global__ __launch_bounds__(256) void global_sa_kernel(
    const float* __restrict__ x2,
    const float* __restrict__ d1x, const float* __restrict__ d1y,
    const float* __restrict__ d1z,
    const float* __restrict__ gw1, const float* __restrict__ gb1,
    const float* __restrict__ gw2, const float* __restrict__ gb2,
    unsigned int* __restrict__ gout) {  // [B][512] as float bits (relu >= 0)
  __shared__ float fin[4][259];
  __shared__ float s[4][256];
  const int t = threadIdx.x;
  const int blk = blockIdx.x;
  const int b = blk / 64;
  const int p0 = (blk % 64) * 4;
  for (int item = t; item < 4 * 259; item += 256) {
    const int p = item / 259, f = item - p * 259;
    float v;
    if (f < 256) {
      v = x2[((size_t)b * 256 + p0 + p) * 256 + f];
    } else {
      const int d = f - 256;
      v = (d == 0 ? d1x : (d == 1 ? d1y : d1z))[(size_t)b * K1 + p0 + p];
    }
    fin[p][f] = v;
  }
  __syncthreads();
  float acc[4] = {0.f, 0.f, 0.f, 0.f};
  for (int f = 0; f < 259; f++) {
    const float w = gw1[f * 256 + t];
#pragma unroll
    for (int p = 0; p < 4; p++) acc[p] = fmaf(fin[p][f], w, acc[p]);
  }
  const float bb = gb1[t];
#pragma unroll
  for (int p = 0; p < 4; p++) s[p][t] = sigmoidf_(acc[p] + bb);
  __syncthreads();
  float a0[4] = {0.f, 0.f, 0.f, 0.f}, a1[4] = {0.f, 0.f, 0.f, 0.f};
  for (int h = 0; h < 256; h++) {
    const float w0 = gw2[h * 512 + t];
    const float w1v = gw2[h * 512 + t + 256];
#pragma unroll
    for (int p = 0; p < 4; p++) {
      a0[p] = fmaf(s[p][h], w0, a0[p]);
      a1[p] = fmaf(s[p][h], w1v, a1[p]);
    }
  }
  const float b0 = gb2[t], b1v = gb2[t + 256];
  float m0 = 0.0f, m1 = 0.0f;  // relu floor
#pragma unroll
  for (int p = 0; p < 4; p++) {
    m0 = fmaxf(m0, fmaxf(a0[p] + b0, 0.0f));
    m1 = fmaxf(m1, fmaxf(a1[p] + b1v, 0.0f));
  }
  atomicMax(&gout[b * 512 + t], __float_as_uint(m0));
  atomicMax(&gout[b * 512 + t + 256], __float_as_uint(m1));
}

// ---------------- Final FC head (float32 output) ----------------
__global__ __launch_bounds__(256) void fc_kernel(
    const unsigned int* __restrict__ g,
    const float* __restrict__ fw1, const float* __restrict__ fb1,
    const float* __restrict__ fw2, const float* __restrict__ fb2,
    float* __restrict__ out) {
  __shared__ float gv[512];
  __shared__ float s[256];
  const int b = blockIdx.x, t = threadIdx.x;
  gv[t] = __uint_as_float(g[b * 512 + t]);
  gv[t + 256] = __uint_as_float(g[b * 512 + t + 256]);
  __syncthreads();
  float acc = 0.0f;
  for (int h = 0; h < 512; h++) acc = fmaf(gv[h], fw1[h * 256 + t], acc);
  s[t] = sigmoidf_(acc + fb1[t]);
  __syncthreads();
  if (t < 128) {
    float a2 = 0.0f;
    for (int h = 0; h < 256; h++) a2 = fmaf(s[h], fw2[h * 128 + t], a2);
    const float o = a2 + fb2[t];
    out[b * 128 + t] = o > 0.0f ? o : 0.0f;
  }
}

}  // namespace

extern "C" void kernel_launch(void* const* d_in, const int* in_sizes, int n_in,
                              void* d_out, int out_size, void* d_ws, size_t ws_size,
                              hipStream_t stream) {
  (void)in_sizes; (void)n_in; (void)out_size; (void)ws_size;
  const float* x     = (const float*)d_in[0];
  const float* pos   = (const float*)d_in[1];
  // d_in[2] = batch (int64) — sorted, equal-sized graphs, unused
  const float* smean = (const float*)d_in[3];
  const float* sstd  = (const float*)d_in[4];
  const float* s1w1  = (const float*)d_in[5];
  const float* s1b1  = (const float*)d_in[6];
  const float* s1w2  = (const float*)d_in[7];
  const float* s1b2  = (const float*)d_in[8];
  const float* s2w1  = (const float*)d_in[9];
  const float* s2b1  = (const float*)d_in[10];
  const float* s2w2  = (const float*)d_in[11];
  const float* s2b2  = (const float*)d_in[12];
  const float* gw1   = (const float*)d_in[13];
  const float* gb1   = (const float*)d_in[14];
  const float* gw2   = (const float*)d_in[15];
  const float* gb2   = (const float*)d_in[16];
  const float* fw1   = (const float*)d_in[17];
  const float* fb1   = (const float*)d_in[18];
  const float* fw2   = (const float*)d_in[19];
  const float* fb2   = (const float*)d_in[20];

  char* ws = (char*)d_ws;
  size_t off = 0;
  auto take = [&](size_t bytes) -> char* {
    char* p = ws + off;
    off = (off + bytes + 255) & ~(size_t)255;
    return p;
  };
  float* pxg         = (float*)take((size_t)NB * N1 * 4);
  float* pyg         = (float*)take((size_t)NB * N1 * 4);
  float* pzg         = (float*)take((size_t)NB * N1 * 4);
  float* d1x         = (float*)take((size_t)NB * K1 * 4);
  float* d1y         = (float*)take((size_t)NB * K1 * 4);
  float* d1z         = (float*)take((size_t)NB * K1 * 4);
  int*   nbr1        = (int*)take((size_t)NB * K1 * MAXN * 4);
  int*   cnt1        = (int*)take((size_t)NB * K1 * 4);
  float* x1          = (float*)take((size_t)NB * K1 * 128 * 4);
  int*   nbr2        = (int*)take((size_t)NB * K2 * MAXN * 4);
  int*   cnt2        = (int*)take((size_t)NB * K2 * 4);
  float* x2          = (float*)take((size_t)NB * K2 * 256 * 4);
  unsigned int* gbuf = (unsigned int*)take((size_t)NB * 512 * 4);

  hipLaunchKernelGGL(fps_l1_kernel, dim3(NB), dim3(256), 0, stream,
                     pos, pxg, pyg, pzg, d1x, d1y, d1z, gbuf);
  hipLaunchKernelGGL(rad12_kernel, dim3(NB * K1 / 4 + NB * K2 / 4), dim3(256), 0, stream,
                     pxg, pyg, pzg, d1x, d1y, d1z, nbr1, cnt1, nbr2, cnt2);
  hipLaunchKernelGGL(conv1_kernel, dim3(NB * K1), dim3(256), 0, stream,
                     x, pxg, pyg, pzg, d1x, d1y, d1z, nbr1, cnt1,
                     s1w1, s1b1, s1w2, s1b2, smean, sstd, x1);
  hipLaunchKernelGGL(conv2_kernel, dim3(NB * K2), dim3(256), 0, stream,
                     x1, d1x, d1y, d1z, nbr2, cnt2,
                     s2w1, s2b1, s2w2, s2b2, x2);
  hipLaunchKernelGGL(global_sa_kernel, dim3(NB * 64), dim3(256), 0, stream,
                     x2, d1x, d1y, d1z, gw1, gb1, gw2, gb2, gbuf);
  hipLaunchKernelGGL(fc_kernel, dim3(NB), dim3(256), 0, stream,
                     gbuf, fw1, fb1, fw2, fb2, (float*)d_out);
}